// Round 6
// baseline (876.192 us; speedup 1.0000x reference)
//
#include <hip/hip_runtime.h>

typedef _Float16 fp16_t;
typedef __attribute__((ext_vector_type(8))) _Float16 f16x8;
typedef __attribute__((ext_vector_type(4))) _Float16 f16x4;
typedef __attribute__((ext_vector_type(4))) float f32x4;

#define N_TOK 8192
#define DIM   1024
#define HID   2048
#define OUTD  1024
#define NE    8
#define NPAIR 16384    // N_TOK * top_k
#define MAXSLOT 72     // m-tiles of 256: 16384/256 + 8 partials
#define HBLK 64        // hist/scatter blocks (256 pairs each)

// -------------------------------------------------------------------------
// async global->LDS, 16B per lane (wave-uniform LDS base + lane*16; global
// address may be per-lane)
// -------------------------------------------------------------------------
__device__ __forceinline__ void load_lds16(const void* g, void* l) {
    __builtin_amdgcn_global_load_lds(
        (__attribute__((address_space(1))) void*)g,
        (__attribute__((address_space(3))) void*)l, 16, 0, 0);
}

// -------------------------------------------------------------------------
// gating: fp32, one wave handles 2 tokens (x rows staged in LDS).
// NO atomics (routing counts derived by hist/scan/scatter below).
// top-2 ties -> lower index (matches jax.lax.top_k); combine weight = the
// ORIGINAL gate value.
// -------------------------------------------------------------------------
__global__ __launch_bounds__(256) void gating_kernel(
    const float* __restrict__ x,  const float* __restrict__ Wg1,
    const float* __restrict__ bg1, const float* __restrict__ Wg2,
    const float* __restrict__ bg2,
    int* __restrict__ top_i, float* __restrict__ top_w)
{
    __shared__ float xs[8][DIM];            // 32 KB: 8 token rows
    const int tid = threadIdx.x, lane = tid & 63, wv = tid >> 6;

    const float4* x4 = (const float4*)(x + (size_t)blockIdx.x * 8 * DIM);
    float4* xs4 = (float4*)&xs[0][0];
    #pragma unroll
    for (int i = 0; i < 8; ++i) xs4[tid + 256 * i] = x4[tid + 256 * i];
    __syncthreads();

    const int trow = wv * 2;                // wave owns tokens trow, trow+1
    const float b = bg1[lane];              // lane owns hidden unit 'lane'
    float h00 = b,   h01 = 0.f;             // token 0: even/odd-quad chains
    float h10 = b,   h11 = 0.f;             // token 1
    for (int d0 = 0; d0 < DIM; d0 += 8) {
        float w[8];
        #pragma unroll
        for (int i = 0; i < 8; ++i) w[i] = Wg1[(d0 + i) * 64 + lane];
        float4 a00 = *(const float4*)&xs[trow][d0];
        float4 a01 = *(const float4*)&xs[trow][d0 + 4];
        float4 a10 = *(const float4*)&xs[trow + 1][d0];
        float4 a11 = *(const float4*)&xs[trow + 1][d0 + 4];
        h00 = fmaf(a00.x, w[0], fmaf(a00.y, w[1], fmaf(a00.z, w[2], fmaf(a00.w, w[3], h00))));
        h01 = fmaf(a01.x, w[4], fmaf(a01.y, w[5], fmaf(a01.z, w[6], fmaf(a01.w, w[7], h01))));
        h10 = fmaf(a10.x, w[0], fmaf(a10.y, w[1], fmaf(a10.z, w[2], fmaf(a10.w, w[3], h10))));
        h11 = fmaf(a11.x, w[4], fmaf(a11.y, w[5], fmaf(a11.z, w[6], fmaf(a11.w, w[7], h11))));
    }
    float hg[2] = { h00 + h01, h10 + h11 };

    #pragma unroll
    for (int t = 0; t < 2; ++t) {
        float h = fmaxf(hg[t], 0.f);
        float p[NE];
        #pragma unroll
        for (int e = 0; e < NE; ++e) p[e] = h * Wg2[lane * NE + e];
        #pragma unroll
        for (int s = 32; s > 0; s >>= 1) {
            #pragma unroll
            for (int e = 0; e < NE; ++e) p[e] += __shfl_xor(p[e], s, 64);
        }
        if (lane == 0) {
            int n = blockIdx.x * 8 + trow + t;
            float g[NE];
            float m = -1e30f;
            #pragma unroll
            for (int e = 0; e < NE; ++e) { g[e] = p[e] + bg2[e]; m = fmaxf(m, g[e]); }
            float s = 0.f;
            #pragma unroll
            for (int e = 0; e < NE; ++e) { g[e] = expf(g[e] - m); s += g[e]; }
            float inv = 1.f / s;
            #pragma unroll
            for (int e = 0; e < NE; ++e) g[e] *= inv;
            int b0 = 0;
            #pragma unroll
            for (int e = 1; e < NE; ++e) if (g[e] > g[b0]) b0 = e;
            int b1 = (b0 == 0) ? 1 : 0;
            #pragma unroll
            for (int e = 0; e < NE; ++e) if (e != b0 && g[e] > g[b1]) b1 = e;
            top_i[n] = b0;          top_i[N_TOK + n] = b1;
            top_w[n] = g[b0];       top_w[N_TOK + n] = g[b1];
        }
    }
}

// -------------------------------------------------------------------------
// hist: per-block expert histogram of the 2N pair stream via wave ballots.
// 64 blocks x 256 threads, 1 pair/thread. Zero atomics.
// -------------------------------------------------------------------------
__global__ __launch_bounds__(256) void hist_kernel(
    const int* __restrict__ top_i, int* __restrict__ blockhist)
{
    __shared__ int wh[4][NE];
    const int tid = threadIdx.x, lane = tid & 63, wv = tid >> 6;
    const int e = top_i[blockIdx.x * 256 + tid];
    #pragma unroll
    for (int e0 = 0; e0 < NE; ++e0) {
        unsigned long long m = __ballot(e == e0);
        if (lane == 0) wh[wv][e0] = __popcll(m);
    }
    __syncthreads();
    if (tid < NE)
        blockhist[blockIdx.x * NE + tid] =
            wh[0][tid] + wh[1][tid] + wh[2][tid] + wh[3][tid];
}

// -------------------------------------------------------------------------
// scan: counts/offs/per-block bases + m-tile table (slot -> expert, m-tile).
// Single block; all in LDS.
// -------------------------------------------------------------------------
__global__ __launch_bounds__(512) void scan_kernel(
    const int* __restrict__ blockhist, int* __restrict__ offs,
    int* __restrict__ pairbase,
    int* __restrict__ tile_e, int* __restrict__ tile_mt)
{
    __shared__ int h[HBLK * NE], pb[HBLK * NE], off_s[NE + 1];
    const int tid = threadIdx.x;
    h[tid] = blockhist[tid];
    __syncthreads();
    if (tid == 0) {
        int c[NE] = {};
        for (int b = 0; b < HBLK; ++b)
            #pragma unroll
            for (int e = 0; e < NE; ++e) { pb[b * NE + e] = c[e]; c[e] += h[b * NE + e]; }
        int acc = 0;
        #pragma unroll
        for (int e = 0; e < NE; ++e) { off_s[e] = acc; acc += c[e]; }
        off_s[NE] = acc;
        for (int e = 0; e <= NE; ++e) offs[e] = off_s[e];
        int s = 0;
        for (int e = 0; e < NE; ++e) {
            int nt = (c[e] + 255) >> 8;
            for (int mt = 0; mt < nt; ++mt) { tile_e[s] = e; tile_mt[s] = mt; ++s; }
        }
        for (; s < MAXSLOT; ++s) tile_e[s] = -1;
    }
    __syncthreads();
    pairbase[tid] = pb[tid] + off_s[tid & (NE - 1)];
}

// -------------------------------------------------------------------------
// scatter: deterministic slot assignment. rank = pairbase[blk][e]
//   + (rank of my wave's earlier waves in this block for e)
//   + (my rank among lanes of my wave with expert e).  Zero atomics.
// -------------------------------------------------------------------------
__global__ __launch_bounds__(256) void scatter_kernel(
    const int* __restrict__ top_i, const int* __restrict__ pairbase,
    int* __restrict__ pair_token, int* __restrict__ slot)
{
    __shared__ int wh[4][NE];
    const int tid = threadIdx.x, lane = tid & 63, wv = tid >> 6;
    const int p = blockIdx.x * 256 + tid;
    const int e = top_i[p];
    int myrank = 0;
    #pragma unroll
    for (int e0 = 0; e0 < NE; ++e0) {
        unsigned long long m = __ballot(e == e0);
        if (lane == 0) wh[wv][e0] = __popcll(m);
        if (e == e0) myrank = __popcll(m & ((1ull << lane) - 1ull));
    }
    __syncthreads();
    int wprefix = 0;
    for (int w = 0; w < wv; ++w) wprefix += wh[w][e];
    const int pout = pairbase[blockIdx.x * NE + e] + wprefix + myrank;
    pair_token[pout] = p & (N_TOK - 1);      // p = s*N + n, N power of two
    slot[p] = pout;
}

// -------------------------------------------------------------------------
__global__ __launch_bounds__(256) void xcvt_kernel(
    const float* __restrict__ x, fp16_t* __restrict__ xb)
{
    size_t i = ((size_t)blockIdx.x * 256 + threadIdx.x) * 4;
    float4 v = *(const float4*)(x + i);
    f16x4 o = { (fp16_t)v.x, (fp16_t)v.y, (fp16_t)v.z, (fp16_t)v.w };
    *(f16x4*)(xb + i) = o;
}

// -------------------------------------------------------------------------
// batched transpose+convert: src fp32 [batch][R][C] -> dst fp16 [batch][C][R]
// -------------------------------------------------------------------------
__global__ __launch_bounds__(256) void transpose_cvt(
    const float* __restrict__ src, fp16_t* __restrict__ dst, int R, int C)
{
    int bb = blockIdx.z;
    src += (size_t)bb * R * C;
    dst += (size_t)bb * R * C;
    __shared__ float sm[32][33];
    int tx = threadIdx.x & 31, ty = threadIdx.x >> 5;   // 32 x 8
    int r0 = blockIdx.y * 32, c0 = blockIdx.x * 32;
    #pragma unroll
    for (int i = 0; i < 4; ++i)
        sm[ty + 8 * i][tx] = src[(size_t)(r0 + ty + 8 * i) * C + c0 + tx];
    __syncthreads();
    #pragma unroll
    for (int i = 0; i < 4; ++i)
        dst[(size_t)(c0 + ty + 8 * i) * R + r0 + tx] = (fp16_t)sm[tx][ty + 8 * i];
}

// -------------------------------------------------------------------------
// expert GEMM, BM=256 x BN=128 tile, BK=32, 8 waves (4M x 2N), per-wave
// 64x64 output (acc = 64 VGPR -> <=128 regs/wave -> 4 waves/SIMD).
// LDS 48 KB double-buffered (A 16K + B 8K per buf) -> 2 blocks/CU.
// Theory: 1-block/CU (prev 128KB config) measured MfmaUtil 30% = 48%
// per-block eff x 0.69 grid packing; 2 blocks/CU attacks both (cross-block
// overlap hides the per-tile vmcnt/barrier + finer grid packs better).
//
// SCHEDULE: proven-safe 2-phase, ONE barrier per K-tile:
//   tile t:  STAGE tile t+1 into buf^1 (3 gload_lds/wave)
//            ds_read + 16 MFMA from buf
//            s_waitcnt vmcnt(0); s_barrier
//   RAW: vmcnt(0)+barrier => t+1 fully in LDS before any wave reads it.
//   WAR: stages into a buffer only after the barrier ending the tile that
//        read it (reads retired via lgkmcnt before MFMA, MFMA before bar).
//
// Swizzle (64B rows = 4 chunks of 16B): stage chunk = (l&3)^((l>>3)&3),
// read slot = quad^((l15>>1)&3)  -> involution; all row-pairs 2-way max
// on LDS banks (2-way is free).
// -------------------------------------------------------------------------
template <int K, int NOUT, bool GATHER, bool RELU, bool OUT_FP16>
__global__ __launch_bounds__(512, 4) void gemm_expert(
    const fp16_t* __restrict__ A, const fp16_t* __restrict__ Wt,
    const float* __restrict__ bias, void* __restrict__ Cout,
    const int* __restrict__ offs, const int* __restrict__ pair_token,
    const int* __restrict__ tile_e, const int* __restrict__ tile_mt)
{
    const int e = tile_e[blockIdx.y];
    if (e < 0) return;
    const int mt  = tile_mt[blockIdx.y];
    const int off = offs[e];
    const int cnt = offs[e + 1] - off;
    const int rows_here = min(256, cnt - mt * 256);
    const int mb = off + mt * 256;
    const int n0 = blockIdx.x * 128;

    extern __shared__ __align__(16) char smem[];   // 49152 B

    const int tid = threadIdx.x, lane = tid & 63, wv = tid >> 6;
    const int wm = wv >> 1, wn = wv & 1;           // 4M x 2N wave grid
    const int l15 = lane & 15, quad = lane >> 4;

    // ---- staging lane constants --------------------------------------
    // wave wv stages A rows [wv*16, +16) and [128+wv*16, +16), B rows
    // [wv*16, +16).  4 lanes per 64B row; lane's chunk is XOR-swizzled.
    const int coff = ((lane & 3) ^ ((lane >> 3) & 3)) * 8;   // elems

    const fp16_t* We = Wt + (size_t)e * NOUT * K;

    const fp16_t* aptr[2];
    #pragma unroll
    for (int s = 0; s < 2; ++s) {
        int tr = wv * 16 + (lane >> 2) + s * 128;
        int rc = (tr < rows_here) ? tr : (rows_here - 1);
        long rowidx = GATHER ? (long)pair_token[mb + rc] : (long)(mb + rc);
        aptr[s] = A + rowidx * (long)K + coff;
    }
    const int nrow = n0 + wv * 16 + (lane >> 2);
    const fp16_t* bptr = We + (size_t)nrow * K + coff;

    char* const asw = smem + wv * 1024;            // A stage base (buf 0)
    char* const bsw = smem + 32768 + wv * 1024;    // B stage base (buf 0)

#define STAGE(kt) do {                                                       \
        int _ab = ((kt) & 1) * 16384;                                        \
        int _bb = ((kt) & 1) * 8192;                                         \
        load_lds16(aptr[0] + (kt) * 32, asw + _ab);                          \
        load_lds16(aptr[1] + (kt) * 32, asw + _ab + 8192);                   \
        load_lds16(bptr    + (kt) * 32, bsw + _bb); } while (0)

    // ---- fragment-read lane constants --------------------------------
    const int slotc = quad ^ ((l15 >> 1) & 3);
    const int arow = (wm * 64 + l15) * 64 + slotc * 16;   // bytes in A-buf
    const int brow = (wn * 64 + l15) * 64 + slotc * 16;   // bytes in B-buf

    f16x8 a[4], b[4];
    f32x4 acc[4][4] = {};

#define READ(buf) do {                                                       \
        _Pragma("unroll")                                                    \
        for (int ii = 0; ii < 4; ++ii)                                       \
            a[ii] = *(const f16x8*)(smem + (buf) * 16384 + arow + ii * 1024);\
        _Pragma("unroll")                                                    \
        for (int jj = 0; jj < 4; ++jj)                                       \
            b[jj] = *(const f16x8*)(smem + 32768 + (buf) * 8192 + brow       \
                                    + jj * 1024); } while (0)

#define MFMA_ALL() do {                                                      \
        _Pragma("unroll")                                                    \
        for (int ii = 0; ii < 4; ++ii)                                       \
        _Pragma("unroll")                                                    \
        for (int jj = 0; jj < 4; ++jj)                                       \
            acc[ii][jj] = __builtin_amdgcn_mfma_f32_16x16x32_f16(            \
                a[ii], b[jj], acc[ii][jj], 0, 0, 0); } while (0)

#define BAR() do { asm volatile("" ::: "memory");                            \
                   __builtin_amdgcn_s_barrier();                             \
                   asm volatile("" ::: "memory"); } while (0)
#define VM0()   asm volatile("s_waitcnt vmcnt(0)" ::: "memory")

    // ---- prologue: stage K-tile 0 into buf0, drain, barrier -----------
    STAGE(0);
    VM0();
    BAR();

    const int ntile = K / 32;
    for (int t = 0; t < ntile; ++t) {
        const int buf = t & 1;
        if (t + 1 < ntile) STAGE(t + 1);   // into buf^1
        READ(buf);
        MFMA_ALL();
        VM0();      // own stages for tile t+1 landed
        BAR();      // everyone's landed; everyone's reads of buf done
    }

#undef STAGE
#undef READ
#undef MFMA_ALL
#undef BAR
#undef VM0

    // ---- epilogue: C/D layout col=lane&15, row=quad*4+reg -------------
    const float* be = bias + (size_t)e * NOUT + n0;
    #pragma unroll
    for (int jj = 0; jj < 4; ++jj) {
        int col = wn * 64 + jj * 16 + l15;
        float bv = be[col];
        #pragma unroll
        for (int ii = 0; ii < 4; ++ii) {
            int mrow0 = wm * 64 + ii * 16 + quad * 4;
            #pragma unroll
            for (int r = 0; r < 4; ++r) {
                int m = mrow0 + r;
                if (m < rows_here) {
                    float v = acc[ii][jj][r] + bv;
                    if (RELU) v = fmaxf(v, 0.f);
                    size_t o = (size_t)(mb + m) * NOUT + n0 + col;
                    if (OUT_FP16) ((fp16_t*)Cout)[o] = (fp16_t)v;
                    else          ((float*)Cout)[o]  = v;
                }
            }
        }
    }
}

// -------------------------------------------------------------------------
__global__ __launch_bounds__(256) void combine_kernel(
    const float* __restrict__ y, const int* __restrict__ slot,
    const float* __restrict__ top_w, float* __restrict__ out)
{
    int idx = blockIdx.x * 256 + threadIdx.x;    // over N_TOK * OUTD/4
    int n  = idx >> 8;                           // OUTD/4 = 256
    int o4 = idx & 255;
    int s0 = slot[n], s1 = slot[N_TOK + n];
    float w0 = top_w[n], w1 = top_w[N_TOK + n];
    float4 y0 = *(const float4*)(y + (size_t)s0 * OUTD + o4 * 4);
    float4 y1 = *(const float4*)(y + (size_t)s1 * OUTD + o4 * 4);
    float4 r;
    r.x = w0 * y0.x + w1 * y1.x;
    r.y = w0 * y0.y + w1 * y1.y;
    r.z = w0 * y0.z + w1 * y1.z;
    r.w = w0 * y0.w + w1 * y1.w;
    *(float4*)(out + (size_t)n * OUTD + o4 * 4) = r;
}

// -------------------------------------------------------------------------
extern "C" void kernel_launch(void* const* d_in, const int* in_sizes, int n_in,
                              void* d_out, int out_size, void* d_ws, size_t ws_size,
                              hipStream_t stream)
{
    (void)in_sizes; (void)n_in; (void)out_size; (void)ws_size;
    const float* x   = (const float*)d_in[0];
    const float* W1  = (const float*)d_in[1];
    const float* b1  = (const float*)d_in[2];
    const float* W2  = (const float*)d_in[3];
    const float* b2  = (const float*)d_in[4];
    const float* W3  = (const float*)d_in[5];
    const float* b3  = (const float*)d_in[6];
    const float* Wg1 = (const float*)d_in[7];
    const float* bg1 = (const float*)d_in[8];
    const float* Wg2 = (const float*)d_in[9];
    const float* bg2 = (const float*)d_in[10];

    // ws layout (bytes):
    //   xb   @ 0          : 16,777,216   (8192x1024 fp16)
    //   h1/y @ 16777216   : 67,108,864   (16384x2048 fp16 == 16384x1024 fp32)
    //   h2   @ 83886080   : 67,108,864
    //   Wt   @ 150994944  : 67,108,864   (max transposed W, fp16)
    //   rt   @ 218103808  : routing (~0.3 MB)
    char* ws = (char*)d_ws;
    fp16_t* xb = (fp16_t*)ws;
    fp16_t* h1 = (fp16_t*)(ws + 16777216);
    fp16_t* h2 = (fp16_t*)(ws + 83886080);
    fp16_t* Wt = (fp16_t*)(ws + 150994944);
    char* rt   = ws + 218103808;
    int*   offs       = (int*)rt;                    // 9
    int*   tile_e     = offs + 9;                    // MAXSLOT
    int*   tile_mt    = tile_e + MAXSLOT;            // MAXSLOT
    int*   top_i      = tile_mt + MAXSLOT;           // 2*N
    float* top_w      = (float*)(top_i + 2 * N_TOK); // 2*N
    int*   slot       = (int*)(top_w + 2 * N_TOK);   // 2*N
    int*   pair_token = slot + 2 * N_TOK;            // NPAIR
    int*   blockhist  = pair_token + NPAIR;          // HBLK*NE
    int*   pairbase   = blockhist + HBLK * NE;       // HBLK*NE

    gating_kernel<<<1024, 256, 0, stream>>>(x, Wg1, bg1, Wg2, bg2, top_i, top_w);
    hist_kernel<<<HBLK, 256, 0, stream>>>(top_i, blockhist);
    scan_kernel<<<1, HBLK * NE, 0, stream>>>(blockhist, offs, pairbase, tile_e, tile_mt);
    scatter_kernel<<<HBLK, 256, 0, stream>>>(top_i, pairbase, pair_token, slot);
    xcvt_kernel<<<8192, 256, 0, stream>>>(x, xb);

    // grid.x = n-tiles so linear%8 ~ n-tile%8 -> per-XCD n-column affinity
    // L1: h1 = relu(x @ W1[e] + b1[e])   (gathered rows, K=1024, NOUT=2048)
    transpose_cvt<<<dim3(HID / 32, DIM / 32, NE), 256, 0, stream>>>(W1, Wt, DIM, HID);
    gemm_expert<DIM, HID, true, true, true>
        <<<dim3(HID / 128, MAXSLOT), 512, 49152, stream>>>(
            xb, Wt, b1, (void*)h1, offs, pair_token, tile_e, tile_mt);

    // L2: h2 = relu(h1 @ W2[e] + b2[e])  (K=2048, NOUT=2048)
    transpose_cvt<<<dim3(HID / 32, HID / 32, NE), 256, 0, stream>>>(W2, Wt, HID, HID);
    gemm_expert<HID, HID, false, true, true>
        <<<dim3(HID / 128, MAXSLOT), 512, 49152, stream>>>(
            h1, Wt, b2, (void*)h2, offs, pair_token, tile_e, tile_mt);

    // L3: y = h2 @ W3[e] + b3[e]  (fp32 out into h1's buffer; K=2048, NOUT=1024)
    transpose_cvt<<<dim3(OUTD / 32, HID / 32, NE), 256, 0, stream>>>(W3, Wt, HID, OUTD);
    gemm_expert<HID, OUTD, false, false, false>
        <<<dim3(OUTD / 128, MAXSLOT), 512, 49152, stream>>>(
            h2, Wt, b3, (void*)h1, offs, pair_token, tile_e, tile_mt);

    combine_kernel<<<8192, 256, 0, stream>>>((const float*)h1, slot, top_w, (float*)d_out);
}

// Round 7
// 858.770 us; speedup vs baseline: 1.0203x; 1.0203x over previous
//
#include <hip/hip_runtime.h>

typedef _Float16 fp16_t;
typedef __attribute__((ext_vector_type(8))) _Float16 f16x8;
typedef __attribute__((ext_vector_type(4))) _Float16 f16x4;
typedef __attribute__((ext_vector_type(4))) float f32x4;

#define N_TOK 8192
#define DIM   1024
#define HID   2048
#define OUTD  1024
#define NE    8
#define NPAIR 16384    // N_TOK * top_k
#define MAXSLOT 72     // m-tiles of 256: 16384/256 + 8 partials
#define HBLK 64        // hist/scatter blocks (256 pairs each)

// -------------------------------------------------------------------------
// async global->LDS, 16B per lane (wave-uniform LDS base + lane*16; global
// address may be per-lane)
// -------------------------------------------------------------------------
__device__ __forceinline__ void load_lds16(const void* g, void* l) {
    __builtin_amdgcn_global_load_lds(
        (__attribute__((address_space(1))) void*)g,
        (__attribute__((address_space(3))) void*)l, 16, 0, 0);
}

// -------------------------------------------------------------------------
// gating: fp32, one wave handles 2 tokens (x rows staged in LDS).
// NO atomics (routing counts derived by hist/scan/scatter below).
// top-2 ties -> lower index (matches jax.lax.top_k); combine weight = the
// ORIGINAL gate value.
// -------------------------------------------------------------------------
__global__ __launch_bounds__(256) void gating_kernel(
    const float* __restrict__ x,  const float* __restrict__ Wg1,
    const float* __restrict__ bg1, const float* __restrict__ Wg2,
    const float* __restrict__ bg2,
    int* __restrict__ top_i, float* __restrict__ top_w)
{
    __shared__ float xs[8][DIM];            // 32 KB: 8 token rows
    const int tid = threadIdx.x, lane = tid & 63, wv = tid >> 6;

    const float4* x4 = (const float4*)(x + (size_t)blockIdx.x * 8 * DIM);
    float4* xs4 = (float4*)&xs[0][0];
    #pragma unroll
    for (int i = 0; i < 8; ++i) xs4[tid + 256 * i] = x4[tid + 256 * i];
    __syncthreads();

    const int trow = wv * 2;                // wave owns tokens trow, trow+1
    const float b = bg1[lane];              // lane owns hidden unit 'lane'
    float h00 = b,   h01 = 0.f;             // token 0: even/odd-quad chains
    float h10 = b,   h11 = 0.f;             // token 1
    for (int d0 = 0; d0 < DIM; d0 += 8) {
        float w[8];
        #pragma unroll
        for (int i = 0; i < 8; ++i) w[i] = Wg1[(d0 + i) * 64 + lane];
        float4 a00 = *(const float4*)&xs[trow][d0];
        float4 a01 = *(const float4*)&xs[trow][d0 + 4];
        float4 a10 = *(const float4*)&xs[trow + 1][d0];
        float4 a11 = *(const float4*)&xs[trow + 1][d0 + 4];
        h00 = fmaf(a00.x, w[0], fmaf(a00.y, w[1], fmaf(a00.z, w[2], fmaf(a00.w, w[3], h00))));
        h01 = fmaf(a01.x, w[4], fmaf(a01.y, w[5], fmaf(a01.z, w[6], fmaf(a01.w, w[7], h01))));
        h10 = fmaf(a10.x, w[0], fmaf(a10.y, w[1], fmaf(a10.z, w[2], fmaf(a10.w, w[3], h10))));
        h11 = fmaf(a11.x, w[4], fmaf(a11.y, w[5], fmaf(a11.z, w[6], fmaf(a11.w, w[7], h11))));
    }
    float hg[2] = { h00 + h01, h10 + h11 };

    #pragma unroll
    for (int t = 0; t < 2; ++t) {
        float h = fmaxf(hg[t], 0.f);
        float p[NE];
        #pragma unroll
        for (int e = 0; e < NE; ++e) p[e] = h * Wg2[lane * NE + e];
        #pragma unroll
        for (int s = 32; s > 0; s >>= 1) {
            #pragma unroll
            for (int e = 0; e < NE; ++e) p[e] += __shfl_xor(p[e], s, 64);
        }
        if (lane == 0) {
            int n = blockIdx.x * 8 + trow + t;
            float g[NE];
            float m = -1e30f;
            #pragma unroll
            for (int e = 0; e < NE; ++e) { g[e] = p[e] + bg2[e]; m = fmaxf(m, g[e]); }
            float s = 0.f;
            #pragma unroll
            for (int e = 0; e < NE; ++e) { g[e] = expf(g[e] - m); s += g[e]; }
            float inv = 1.f / s;
            #pragma unroll
            for (int e = 0; e < NE; ++e) g[e] *= inv;
            int b0 = 0;
            #pragma unroll
            for (int e = 1; e < NE; ++e) if (g[e] > g[b0]) b0 = e;
            int b1 = (b0 == 0) ? 1 : 0;
            #pragma unroll
            for (int e = 0; e < NE; ++e) if (e != b0 && g[e] > g[b1]) b1 = e;
            top_i[n] = b0;          top_i[N_TOK + n] = b1;
            top_w[n] = g[b0];       top_w[N_TOK + n] = g[b1];
        }
    }
}

// -------------------------------------------------------------------------
// hist: per-block expert histogram of the 2N pair stream via wave ballots.
// 64 blocks x 256 threads, 1 pair/thread. Zero atomics.
// -------------------------------------------------------------------------
__global__ __launch_bounds__(256) void hist_kernel(
    const int* __restrict__ top_i, int* __restrict__ blockhist)
{
    __shared__ int wh[4][NE];
    const int tid = threadIdx.x, lane = tid & 63, wv = tid >> 6;
    const int e = top_i[blockIdx.x * 256 + tid];
    #pragma unroll
    for (int e0 = 0; e0 < NE; ++e0) {
        unsigned long long m = __ballot(e == e0);
        if (lane == 0) wh[wv][e0] = __popcll(m);
    }
    __syncthreads();
    if (tid < NE)
        blockhist[blockIdx.x * NE + tid] =
            wh[0][tid] + wh[1][tid] + wh[2][tid] + wh[3][tid];
}

// -------------------------------------------------------------------------
// scan: counts/offs/per-block bases + m-tile table (slot -> expert, m-tile).
// Single block; all in LDS.
// -------------------------------------------------------------------------
__global__ __launch_bounds__(512) void scan_kernel(
    const int* __restrict__ blockhist, int* __restrict__ offs,
    int* __restrict__ pairbase,
    int* __restrict__ tile_e, int* __restrict__ tile_mt)
{
    __shared__ int h[HBLK * NE], pb[HBLK * NE], off_s[NE + 1];
    const int tid = threadIdx.x;
    h[tid] = blockhist[tid];
    __syncthreads();
    if (tid == 0) {
        int c[NE] = {};
        for (int b = 0; b < HBLK; ++b)
            #pragma unroll
            for (int e = 0; e < NE; ++e) { pb[b * NE + e] = c[e]; c[e] += h[b * NE + e]; }
        int acc = 0;
        #pragma unroll
        for (int e = 0; e < NE; ++e) { off_s[e] = acc; acc += c[e]; }
        off_s[NE] = acc;
        for (int e = 0; e <= NE; ++e) offs[e] = off_s[e];
        int s = 0;
        for (int e = 0; e < NE; ++e) {
            int nt = (c[e] + 255) >> 8;
            for (int mt = 0; mt < nt; ++mt) { tile_e[s] = e; tile_mt[s] = mt; ++s; }
        }
        for (; s < MAXSLOT; ++s) tile_e[s] = -1;
    }
    __syncthreads();
    pairbase[tid] = pb[tid] + off_s[tid & (NE - 1)];
}

// -------------------------------------------------------------------------
// scatter: deterministic slot assignment. rank = pairbase[blk][e]
//   + (rank of my wave's earlier waves in this block for e)
//   + (my rank among lanes of my wave with expert e).  Zero atomics.
// -------------------------------------------------------------------------
__global__ __launch_bounds__(256) void scatter_kernel(
    const int* __restrict__ top_i, const int* __restrict__ pairbase,
    int* __restrict__ pair_token, int* __restrict__ slot)
{
    __shared__ int wh[4][NE];
    const int tid = threadIdx.x, lane = tid & 63, wv = tid >> 6;
    const int p = blockIdx.x * 256 + tid;
    const int e = top_i[p];
    int myrank = 0;
    #pragma unroll
    for (int e0 = 0; e0 < NE; ++e0) {
        unsigned long long m = __ballot(e == e0);
        if (lane == 0) wh[wv][e0] = __popcll(m);
        if (e == e0) myrank = __popcll(m & ((1ull << lane) - 1ull));
    }
    __syncthreads();
    int wprefix = 0;
    for (int w = 0; w < wv; ++w) wprefix += wh[w][e];
    const int pout = pairbase[blockIdx.x * NE + e] + wprefix + myrank;
    pair_token[pout] = p & (N_TOK - 1);      // p = s*N + n, N power of two
    slot[p] = pout;
}

// -------------------------------------------------------------------------
__global__ __launch_bounds__(256) void xcvt_kernel(
    const float* __restrict__ x, fp16_t* __restrict__ xb)
{
    size_t i = ((size_t)blockIdx.x * 256 + threadIdx.x) * 4;
    float4 v = *(const float4*)(x + i);
    f16x4 o = { (fp16_t)v.x, (fp16_t)v.y, (fp16_t)v.z, (fp16_t)v.w };
    *(f16x4*)(xb + i) = o;
}

// -------------------------------------------------------------------------
// batched transpose+convert: src fp32 [batch][R][C] -> dst fp16 [batch][C][R]
// -------------------------------------------------------------------------
__global__ __launch_bounds__(256) void transpose_cvt(
    const float* __restrict__ src, fp16_t* __restrict__ dst, int R, int C)
{
    int bb = blockIdx.z;
    src += (size_t)bb * R * C;
    dst += (size_t)bb * R * C;
    __shared__ float sm[32][33];
    int tx = threadIdx.x & 31, ty = threadIdx.x >> 5;   // 32 x 8
    int r0 = blockIdx.y * 32, c0 = blockIdx.x * 32;
    #pragma unroll
    for (int i = 0; i < 4; ++i)
        sm[ty + 8 * i][tx] = src[(size_t)(r0 + ty + 8 * i) * C + c0 + tx];
    __syncthreads();
    #pragma unroll
    for (int i = 0; i < 4; ++i)
        dst[(size_t)(c0 + ty + 8 * i) * R + r0 + tx] = (fp16_t)sm[tx][ty + 8 * i];
}

// -------------------------------------------------------------------------
// expert GEMM, 256x256 8-phase counted-vmcnt template (learn_hip m201-style)
//
//   512 threads = 8 waves (2M x 4N); per-wave output 128x64; BK=64.
//   LDS 128 KiB: [buf][A/B][half][128 rows][64 f16], double-buffered per
//   K-tile.  Swizzle: stage chunk = (tid&7)^(rowsel&7) on the GLOBAL source
//   (involution), un-applied on the ds_read side -> 2-way max bank aliasing.
//
//   Iteration = 2 K-tiles (kt0=2i -> buf0, kt1 -> buf1), 8 phases, each:
//     {ds_read subtile | issue 1 half-tile prefetch} ; s_barrier ;
//     lgkmcnt(0) ; setprio(1) ; 16 MFMA ; setprio(0) ; [vmcnt @p4/p8] ;
//     s_barrier
//   Stage map: p1:A1(kt1)  p2:A0(kt0+2) p3:B0(kt0+2) p4:B1(kt0+2)
//              p5:A1(kt0+2) p6:A0(kt0+3) p7:B0(kt0+3) p8:B1(kt0+3)
//   vmcnt ledger (loads retire in issue order):
//     steady p4: 14 outstanding, vmcnt(6) retires 8 = ALL of kt1  -> p5 ok
//     steady p8: 14 outstanding, vmcnt(6) retires 8 = ALL of kt0+2 -> p1 ok
//   RACE FIX (R4 post-timing divergence root cause): in the FINAL iteration
//   the pf-gated stages are skipped, so p4 sees only 8 outstanding and
//   vmcnt(6) retired just 2 -> kt1's B0/B1/A1 could be read before landing
//   (latency-dependent; bit only under warm replay).  Final iteration now
//   drains with vmcnt(0) at p4 (and p8, trivially).
//   WAR safety: every stage targets a slot whose last reader phase ended
//   >=1 barrier earlier, and each phase's LGKM0 precedes its end barrier.
// -------------------------------------------------------------------------
template <int K, int NOUT, bool GATHER, bool RELU, bool OUT_FP16>
__global__ __launch_bounds__(512) void gemm_expert(
    const fp16_t* __restrict__ A, const fp16_t* __restrict__ Wt,
    const float* __restrict__ bias, void* __restrict__ Cout,
    const int* __restrict__ offs, const int* __restrict__ pair_token,
    const int* __restrict__ tile_e, const int* __restrict__ tile_mt)
{
    const int e = tile_e[blockIdx.y];
    if (e < 0) return;
    const int mt  = tile_mt[blockIdx.y];
    const int off = offs[e];
    const int cnt = offs[e + 1] - off;
    const int rows_here = min(256, cnt - mt * 256);
    const int mb = off + mt * 256;
    const int n0 = blockIdx.x * 256;

    extern __shared__ __align__(16) char smem[];   // 131072 B

    const int tid = threadIdx.x, lane = tid & 63, wv = tid >> 6;
    const int wm = wv >> 2, wn = wv & 3;           // 2M x 4N wave grid
    const int l15 = lane & 15, quad = lane >> 4, sb = l15 & 7;

    // ---- staging lane constants --------------------------------------
    const int rowsel = tid >> 3;                         // 0..63
    const int coff = ((tid & 7) ^ (rowsel & 7)) * 8;     // swizzled chunk (elems)

    const fp16_t* We = Wt + (size_t)e * NOUT * K;

    // A stage pointers [half][substep]: tile row = rowsel + s*128 + h*64
    const fp16_t* aptr[2][2];
    #pragma unroll
    for (int h = 0; h < 2; ++h)
        #pragma unroll
        for (int s = 0; s < 2; ++s) {
            int tr = rowsel + s * 128 + h * 64;
            int rc = (tr < rows_here) ? tr : (rows_here - 1);
            long rowidx = GATHER ? (long)pair_token[mb + rc] : (long)(mb + rc);
            aptr[h][s] = A + rowidx * (long)K + coff;
        }
    // B stage base: n-row = n0 + nbase + s*128 + h*32
    const int nbase = (rowsel & 31) + (tid >> 8) * 64;
    const fp16_t* bptr = We + (size_t)(n0 + nbase) * K + coff;

    char* const ldsw = smem + wv * 1024;               // per-wave stage base

#define STAGE_A(h, kt) do {                                                  \
        int _b = ((kt) & 1) * 32768 + (h) * 16384;                           \
        load_lds16(aptr[h][0] + (kt) * 64, ldsw + _b);                       \
        load_lds16(aptr[h][1] + (kt) * 64, ldsw + _b + 8192); } while (0)

#define STAGE_B(h, kt) do {                                                  \
        int _b = 65536 + ((kt) & 1) * 32768 + (h) * 16384;                   \
        load_lds16(bptr + (size_t)((h) * 32) * K + (kt) * 64, ldsw + _b);    \
        load_lds16(bptr + (size_t)((h) * 32 + 128) * K + (kt) * 64,          \
                   ldsw + _b + 8192); } while (0)

    // ---- fragment-read lane constants --------------------------------
    const int slot0 = (quad ^ sb) * 16;            // ks=0 k-chunk slot
    const int slot1 = ((quad + 4) ^ sb) * 16;      // ks=1
    const int arow = (wm * 64 + l15) * 128;        // row-in-half * 128B
    const int brow = (wn * 32 + l15) * 128;

    f16x8 a[4][2], b0[2][2], b1[2][2];
    f32x4 acc[8][4] = {};

#define READ_A(buf, h) do {                                                  \
        _Pragma("unroll")                                                    \
        for (int ii = 0; ii < 4; ++ii) {                                     \
            int _b = (buf) * 32768 + (h) * 16384 + arow + ii * 2048;         \
            a[ii][0] = *(const f16x8*)(smem + _b + slot0);                   \
            a[ii][1] = *(const f16x8*)(smem + _b + slot1);                   \
        } } while (0)

#define READ_B(buf, h, br) do {                                              \
        _Pragma("unroll")                                                    \
        for (int jj = 0; jj < 2; ++jj) {                                     \
            int _b = 65536 + (buf) * 32768 + (h) * 16384 + brow + jj * 2048; \
            br[jj][0] = *(const f16x8*)(smem + _b + slot0);                  \
            br[jj][1] = *(const f16x8*)(smem + _b + slot1);                  \
        } } while (0)

#define MFMA_Q(imb, jnb, br) do {                                            \
        _Pragma("unroll")                                                    \
        for (int ks = 0; ks < 2; ++ks)                                       \
        _Pragma("unroll")                                                    \
        for (int ii = 0; ii < 4; ++ii)                                       \
        _Pragma("unroll")                                                    \
        for (int jj = 0; jj < 2; ++jj)                                       \
            acc[(imb) + ii][(jnb) + jj] =                                    \
                __builtin_amdgcn_mfma_f32_16x16x32_f16(                      \
                    a[ii][ks], br[jj][ks], acc[(imb) + ii][(jnb) + jj],      \
                    0, 0, 0); } while (0)

#define BAR() do { asm volatile("" ::: "memory");                            \
                   __builtin_amdgcn_s_barrier();                             \
                   asm volatile("" ::: "memory"); } while (0)
#define LGKM0() asm volatile("s_waitcnt lgkmcnt(0)" ::: "memory")
#define VM6()   asm volatile("s_waitcnt vmcnt(6)" ::: "memory")
#define VM0()   asm volatile("s_waitcnt vmcnt(0)" ::: "memory")

    // ---- prologue: K-tile 0 fully + A0,B0,B1 of K-tile 1 --------------
    STAGE_A(0, 0); STAGE_B(0, 0); STAGE_B(1, 0); STAGE_A(1, 0);   // 8 loads
    STAGE_A(0, 1); STAGE_B(0, 1); STAGE_B(1, 1);                  // 6 loads
    VM6();          // 14 -> 6: all of K-tile 0 landed; kt1's 6 in flight
    BAR();

    const int niter = K / 128;
    for (int i = 0; i < niter; ++i) {
        const int kt0 = 2 * i, kt1 = kt0 + 1;
        const bool pf = (i + 1 < niter);
        // p1: quadrant (m0..3, n0..1) of kt0
        READ_A(0, 0); READ_B(0, 0, b0);
        STAGE_A(1, kt1);
        BAR(); LGKM0();
        __builtin_amdgcn_s_setprio(1); MFMA_Q(0, 0, b0); __builtin_amdgcn_s_setprio(0);
        BAR();
        // p2: (m0..3, n2..3)
        READ_B(0, 1, b1);
        if (pf) STAGE_A(0, kt0 + 2);
        BAR(); LGKM0();
        __builtin_amdgcn_s_setprio(1); MFMA_Q(0, 2, b1); __builtin_amdgcn_s_setprio(0);
        BAR();
        // p3: (m4..7, n2..3)
        READ_A(0, 1);
        if (pf) STAGE_B(0, kt0 + 2);
        BAR(); LGKM0();
        __builtin_amdgcn_s_setprio(1); MFMA_Q(4, 2, b1); __builtin_amdgcn_s_setprio(0);
        BAR();
        // p4: (m4..7, n0..1)  -- no new ds_reads
        if (pf) STAGE_B(1, kt0 + 2);
        BAR();
        __builtin_amdgcn_s_setprio(1); MFMA_Q(4, 0, b0); __builtin_amdgcn_s_setprio(0);
        if (pf) VM6(); else VM0();   // ALL of kt1 landed before p5 reads it
        BAR();
        // p5: (m0..3, n0..1) of kt1
        READ_A(1, 0); READ_B(1, 0, b0);
        if (pf) STAGE_A(1, kt0 + 2);
        BAR(); LGKM0();
        __builtin_amdgcn_s_setprio(1); MFMA_Q(0, 0, b0); __builtin_amdgcn_s_setprio(0);
        BAR();
        // p6: (m0..3, n2..3)
        READ_B(1, 1, b1);
        if (pf) STAGE_A(0, kt0 + 3);
        BAR(); LGKM0();
        __builtin_amdgcn_s_setprio(1); MFMA_Q(0, 2, b1); __builtin_amdgcn_s_setprio(0);
        BAR();
        // p7: (m4..7, n2..3)
        READ_A(1, 1);
        if (pf) STAGE_B(0, kt0 + 3);
        BAR(); LGKM0();
        __builtin_amdgcn_s_setprio(1); MFMA_Q(4, 2, b1); __builtin_amdgcn_s_setprio(0);
        BAR();
        // p8: (m4..7, n0..1)
        if (pf) STAGE_B(1, kt0 + 3);
        BAR();
        __builtin_amdgcn_s_setprio(1); MFMA_Q(4, 0, b0); __builtin_amdgcn_s_setprio(0);
        if (pf) VM6(); else VM0();   // ALL of kt0+2 landed before next p1
        BAR();
    }

#undef STAGE_A
#undef STAGE_B
#undef READ_A
#undef READ_B
#undef MFMA_Q
#undef BAR
#undef LGKM0
#undef VM6
#undef VM0

    // ---- epilogue: C/D layout col=lane&15, row=quad*4+reg -------------
    const float* be = bias + (size_t)e * NOUT + n0;
    #pragma unroll
    for (int j = 0; j < 4; ++j) {
        int col = wn * 64 + j * 16 + l15;
        float bv = be[col];
        #pragma unroll
        for (int i2 = 0; i2 < 8; ++i2) {
            int mrow0 = wm * 128 + i2 * 16 + quad * 4;
            #pragma unroll
            for (int r = 0; r < 4; ++r) {
                int m = mrow0 + r;
                if (m < rows_here) {
                    float v = acc[i2][j][r] + bv;
                    if (RELU) v = fmaxf(v, 0.f);
                    size_t o = (size_t)(mb + m) * NOUT + n0 + col;
                    if (OUT_FP16) ((fp16_t*)Cout)[o] = (fp16_t)v;
                    else          ((float*)Cout)[o]  = v;
                }
            }
        }
    }
}

// -------------------------------------------------------------------------
__global__ __launch_bounds__(256) void combine_kernel(
    const float* __restrict__ y, const int* __restrict__ slot,
    const float* __restrict__ top_w, float* __restrict__ out)
{
    int idx = blockIdx.x * 256 + threadIdx.x;    // over N_TOK * OUTD/4
    int n  = idx >> 8;                           // OUTD/4 = 256
    int o4 = idx & 255;
    int s0 = slot[n], s1 = slot[N_TOK + n];
    float w0 = top_w[n], w1 = top_w[N_TOK + n];
    float4 y0 = *(const float4*)(y + (size_t)s0 * OUTD + o4 * 4);
    float4 y1 = *(const float4*)(y + (size_t)s1 * OUTD + o4 * 4);
    float4 r;
    r.x = w0 * y0.x + w1 * y1.x;
    r.y = w0 * y0.y + w1 * y1.y;
    r.z = w0 * y0.z + w1 * y1.z;
    r.w = w0 * y0.w + w1 * y1.w;
    *(float4*)(out + (size_t)n * OUTD + o4 * 4) = r;
}

// -------------------------------------------------------------------------
extern "C" void kernel_launch(void* const* d_in, const int* in_sizes, int n_in,
                              void* d_out, int out_size, void* d_ws, size_t ws_size,
                              hipStream_t stream)
{
    (void)in_sizes; (void)n_in; (void)out_size; (void)ws_size;
    const float* x   = (const float*)d_in[0];
    const float* W1  = (const float*)d_in[1];
    const float* b1  = (const float*)d_in[2];
    const float* W2  = (const float*)d_in[3];
    const float* b2  = (const float*)d_in[4];
    const float* W3  = (const float*)d_in[5];
    const float* b3  = (const float*)d_in[6];
    const float* Wg1 = (const float*)d_in[7];
    const float* bg1 = (const float*)d_in[8];
    const float* Wg2 = (const float*)d_in[9];
    const float* bg2 = (const float*)d_in[10];

    // ws layout (bytes):
    //   xb   @ 0          : 16,777,216   (8192x1024 fp16)
    //   h1/y @ 16777216   : 67,108,864   (16384x2048 fp16 == 16384x1024 fp32)
    //   h2   @ 83886080   : 67,108,864
    //   Wt   @ 150994944  : 67,108,864   (max transposed W, fp16)
    //   rt   @ 218103808  : routing (~0.3 MB)
    char* ws = (char*)d_ws;
    fp16_t* xb = (fp16_t*)ws;
    fp16_t* h1 = (fp16_t*)(ws + 16777216);
    fp16_t* h2 = (fp16_t*)(ws + 83886080);
    fp16_t* Wt = (fp16_t*)(ws + 150994944);
    char* rt   = ws + 218103808;
    int*   offs       = (int*)rt;                    // 9
    int*   tile_e     = offs + 9;                    // MAXSLOT
    int*   tile_mt    = tile_e + MAXSLOT;            // MAXSLOT
    int*   top_i      = tile_mt + MAXSLOT;           // 2*N
    float* top_w      = (float*)(top_i + 2 * N_TOK); // 2*N
    int*   slot       = (int*)(top_w + 2 * N_TOK);   // 2*N
    int*   pair_token = slot + 2 * N_TOK;            // NPAIR
    int*   blockhist  = pair_token + NPAIR;          // HBLK*NE
    int*   pairbase   = blockhist + HBLK * NE;       // HBLK*NE

    gating_kernel<<<1024, 256, 0, stream>>>(x, Wg1, bg1, Wg2, bg2, top_i, top_w);
    hist_kernel<<<HBLK, 256, 0, stream>>>(top_i, blockhist);
    scan_kernel<<<1, HBLK * NE, 0, stream>>>(blockhist, offs, pairbase, tile_e, tile_mt);
    scatter_kernel<<<HBLK, 256, 0, stream>>>(top_i, pairbase, pair_token, slot);
    xcvt_kernel<<<8192, 256, 0, stream>>>(x, xb);

    // grid.x = n-tiles so linear%8 ~ n-tile%8 -> per-XCD n-column affinity
    // L1: h1 = relu(x @ W1[e] + b1[e])   (gathered rows, K=1024, NOUT=2048)
    transpose_cvt<<<dim3(HID / 32, DIM / 32, NE), 256, 0, stream>>>(W1, Wt, DIM, HID);
    gemm_expert<DIM, HID, true, true, true>
        <<<dim3(HID / 256, MAXSLOT), 512, 131072, stream>>>(
            xb, Wt, b1, (void*)h1, offs, pair_token, tile_e, tile_mt);

    // L2: h2 = relu(h1 @ W2[e] + b2[e])  (K=2048, NOUT=2048)
    transpose_cvt<<<dim3(HID / 32, HID / 32, NE), 256, 0, stream>>>(W2, Wt, HID, HID);
    gemm_expert<HID, HID, false, true, true>
        <<<dim3(HID / 256, MAXSLOT), 512, 131072, stream>>>(
            h1, Wt, b2, (void*)h2, offs, pair_token, tile_e, tile_mt);

    // L3: y = h2 @ W3[e] + b3[e]  (fp32 out into h1's buffer; K=2048, NOUT=1024)
    transpose_cvt<<<dim3(OUTD / 32, HID / 32, NE), 256, 0, stream>>>(W3, Wt, HID, OUTD);
    gemm_expert<HID, OUTD, false, false, false>
        <<<dim3(OUTD / 256, MAXSLOT), 512, 131072, stream>>>(
            h2, Wt, b3, (void*)h1, offs, pair_token, tile_e, tile_mt);

    combine_kernel<<<8192, 256, 0, stream>>>((const float*)h1, slot, top_w, (float*)d_out);
}

// Round 8
// 772.478 us; speedup vs baseline: 1.1343x; 1.1117x over previous
//
#include <hip/hip_runtime.h>

typedef _Float16 fp16_t;
typedef __attribute__((ext_vector_type(8))) _Float16 f16x8;
typedef __attribute__((ext_vector_type(4))) _Float16 f16x4;
typedef __attribute__((ext_vector_type(4))) float f32x4;

#define N_TOK 8192
#define DIM   1024
#define HID   2048
#define OUTD  1024
#define NE    8
#define NPAIR 16384    // N_TOK * top_k
#define MAXSLOT 72     // m-tiles of 256: 16384/256 + 8 partials
#define HBLK 64        // hist/scatter blocks (256 pairs each)

// -------------------------------------------------------------------------
// async global->LDS, 16B per lane (wave-uniform LDS base + lane*16; global
// address may be per-lane)
// -------------------------------------------------------------------------
__device__ __forceinline__ void load_lds16(const void* g, void* l) {
    __builtin_amdgcn_global_load_lds(
        (__attribute__((address_space(1))) void*)g,
        (__attribute__((address_space(3))) void*)l, 16, 0, 0);
}

// -------------------------------------------------------------------------
// gating: fp32, one wave handles 2 tokens (x rows staged in LDS).
// NO atomics (routing counts derived by hist/scan/scatter below).
// top-2 ties -> lower index (matches jax.lax.top_k); combine weight = the
// ORIGINAL gate value.
// -------------------------------------------------------------------------
__global__ __launch_bounds__(256) void gating_kernel(
    const float* __restrict__ x,  const float* __restrict__ Wg1,
    const float* __restrict__ bg1, const float* __restrict__ Wg2,
    const float* __restrict__ bg2,
    int* __restrict__ top_i, float* __restrict__ top_w)
{
    __shared__ float xs[8][DIM];            // 32 KB: 8 token rows
    const int tid = threadIdx.x, lane = tid & 63, wv = tid >> 6;

    const float4* x4 = (const float4*)(x + (size_t)blockIdx.x * 8 * DIM);
    float4* xs4 = (float4*)&xs[0][0];
    #pragma unroll
    for (int i = 0; i < 8; ++i) xs4[tid + 256 * i] = x4[tid + 256 * i];
    __syncthreads();

    const int trow = wv * 2;                // wave owns tokens trow, trow+1
    const float b = bg1[lane];              // lane owns hidden unit 'lane'
    float h00 = b,   h01 = 0.f;             // token 0: even/odd-quad chains
    float h10 = b,   h11 = 0.f;             // token 1
    for (int d0 = 0; d0 < DIM; d0 += 8) {
        float w[8];
        #pragma unroll
        for (int i = 0; i < 8; ++i) w[i] = Wg1[(d0 + i) * 64 + lane];
        float4 a00 = *(const float4*)&xs[trow][d0];
        float4 a01 = *(const float4*)&xs[trow][d0 + 4];
        float4 a10 = *(const float4*)&xs[trow + 1][d0];
        float4 a11 = *(const float4*)&xs[trow + 1][d0 + 4];
        h00 = fmaf(a00.x, w[0], fmaf(a00.y, w[1], fmaf(a00.z, w[2], fmaf(a00.w, w[3], h00))));
        h01 = fmaf(a01.x, w[4], fmaf(a01.y, w[5], fmaf(a01.z, w[6], fmaf(a01.w, w[7], h01))));
        h10 = fmaf(a10.x, w[0], fmaf(a10.y, w[1], fmaf(a10.z, w[2], fmaf(a10.w, w[3], h10))));
        h11 = fmaf(a11.x, w[4], fmaf(a11.y, w[5], fmaf(a11.z, w[6], fmaf(a11.w, w[7], h11))));
    }
    float hg[2] = { h00 + h01, h10 + h11 };

    #pragma unroll
    for (int t = 0; t < 2; ++t) {
        float h = fmaxf(hg[t], 0.f);
        float p[NE];
        #pragma unroll
        for (int e = 0; e < NE; ++e) p[e] = h * Wg2[lane * NE + e];
        #pragma unroll
        for (int s = 32; s > 0; s >>= 1) {
            #pragma unroll
            for (int e = 0; e < NE; ++e) p[e] += __shfl_xor(p[e], s, 64);
        }
        if (lane == 0) {
            int n = blockIdx.x * 8 + trow + t;
            float g[NE];
            float m = -1e30f;
            #pragma unroll
            for (int e = 0; e < NE; ++e) { g[e] = p[e] + bg2[e]; m = fmaxf(m, g[e]); }
            float s = 0.f;
            #pragma unroll
            for (int e = 0; e < NE; ++e) { g[e] = expf(g[e] - m); s += g[e]; }
            float inv = 1.f / s;
            #pragma unroll
            for (int e = 0; e < NE; ++e) g[e] *= inv;
            int b0 = 0;
            #pragma unroll
            for (int e = 1; e < NE; ++e) if (g[e] > g[b0]) b0 = e;
            int b1 = (b0 == 0) ? 1 : 0;
            #pragma unroll
            for (int e = 0; e < NE; ++e) if (e != b0 && g[e] > g[b1]) b1 = e;
            top_i[n] = b0;          top_i[N_TOK + n] = b1;
            top_w[n] = g[b0];       top_w[N_TOK + n] = g[b1];
        }
    }
}

// -------------------------------------------------------------------------
// hist: per-block expert histogram of the 2N pair stream via wave ballots.
// 64 blocks x 256 threads, 1 pair/thread. Zero atomics.
// -------------------------------------------------------------------------
__global__ __launch_bounds__(256) void hist_kernel(
    const int* __restrict__ top_i, int* __restrict__ blockhist)
{
    __shared__ int wh[4][NE];
    const int tid = threadIdx.x, lane = tid & 63, wv = tid >> 6;
    const int e = top_i[blockIdx.x * 256 + tid];
    #pragma unroll
    for (int e0 = 0; e0 < NE; ++e0) {
        unsigned long long m = __ballot(e == e0);
        if (lane == 0) wh[wv][e0] = __popcll(m);
    }
    __syncthreads();
    if (tid < NE)
        blockhist[blockIdx.x * NE + tid] =
            wh[0][tid] + wh[1][tid] + wh[2][tid] + wh[3][tid];
}

// -------------------------------------------------------------------------
// scan: counts/offs/per-block bases + m-tile table (slot -> expert, m-tile).
// Single block; all in LDS.
// -------------------------------------------------------------------------
__global__ __launch_bounds__(512) void scan_kernel(
    const int* __restrict__ blockhist, int* __restrict__ offs,
    int* __restrict__ pairbase,
    int* __restrict__ tile_e, int* __restrict__ tile_mt)
{
    __shared__ int h[HBLK * NE], pb[HBLK * NE], off_s[NE + 1];
    const int tid = threadIdx.x;
    h[tid] = blockhist[tid];
    __syncthreads();
    if (tid == 0) {
        int c[NE] = {};
        for (int b = 0; b < HBLK; ++b)
            #pragma unroll
            for (int e = 0; e < NE; ++e) { pb[b * NE + e] = c[e]; c[e] += h[b * NE + e]; }
        int acc = 0;
        #pragma unroll
        for (int e = 0; e < NE; ++e) { off_s[e] = acc; acc += c[e]; }
        off_s[NE] = acc;
        for (int e = 0; e <= NE; ++e) offs[e] = off_s[e];
        int s = 0;
        for (int e = 0; e < NE; ++e) {
            int nt = (c[e] + 255) >> 8;
            for (int mt = 0; mt < nt; ++mt) { tile_e[s] = e; tile_mt[s] = mt; ++s; }
        }
        for (; s < MAXSLOT; ++s) tile_e[s] = -1;
    }
    __syncthreads();
    pairbase[tid] = pb[tid] + off_s[tid & (NE - 1)];
}

// -------------------------------------------------------------------------
// scatter: deterministic slot assignment. rank = pairbase[blk][e]
//   + (rank of my wave's earlier waves in this block for e)
//   + (my rank among lanes of my wave with expert e).  Zero atomics.
// -------------------------------------------------------------------------
__global__ __launch_bounds__(256) void scatter_kernel(
    const int* __restrict__ top_i, const int* __restrict__ pairbase,
    int* __restrict__ pair_token, int* __restrict__ slot)
{
    __shared__ int wh[4][NE];
    const int tid = threadIdx.x, lane = tid & 63, wv = tid >> 6;
    const int p = blockIdx.x * 256 + tid;
    const int e = top_i[p];
    int myrank = 0;
    #pragma unroll
    for (int e0 = 0; e0 < NE; ++e0) {
        unsigned long long m = __ballot(e == e0);
        if (lane == 0) wh[wv][e0] = __popcll(m);
        if (e == e0) myrank = __popcll(m & ((1ull << lane) - 1ull));
    }
    __syncthreads();
    int wprefix = 0;
    for (int w = 0; w < wv; ++w) wprefix += wh[w][e];
    const int pout = pairbase[blockIdx.x * NE + e] + wprefix + myrank;
    pair_token[pout] = p & (N_TOK - 1);      // p = s*N + n, N power of two
    slot[p] = pout;
}

// -------------------------------------------------------------------------
__global__ __launch_bounds__(256) void xcvt_kernel(
    const float* __restrict__ x, fp16_t* __restrict__ xb)
{
    size_t i = ((size_t)blockIdx.x * 256 + threadIdx.x) * 4;
    float4 v = *(const float4*)(x + i);
    f16x4 o = { (fp16_t)v.x, (fp16_t)v.y, (fp16_t)v.z, (fp16_t)v.w };
    *(f16x4*)(xb + i) = o;
}

// -------------------------------------------------------------------------
// batched transpose+convert: src fp32 [batch][R][C] -> dst fp16 [batch][C][R]
// -------------------------------------------------------------------------
__global__ __launch_bounds__(256) void transpose_cvt(
    const float* __restrict__ src, fp16_t* __restrict__ dst, int R, int C)
{
    int bb = blockIdx.z;
    src += (size_t)bb * R * C;
    dst += (size_t)bb * R * C;
    __shared__ float sm[32][33];
    int tx = threadIdx.x & 31, ty = threadIdx.x >> 5;   // 32 x 8
    int r0 = blockIdx.y * 32, c0 = blockIdx.x * 32;
    #pragma unroll
    for (int i = 0; i < 4; ++i)
        sm[ty + 8 * i][tx] = src[(size_t)(r0 + ty + 8 * i) * C + c0 + tx];
    __syncthreads();
    #pragma unroll
    for (int i = 0; i < 4; ++i)
        dst[(size_t)(c0 + ty + 8 * i) * R + r0 + tx] = (fp16_t)sm[tx][ty + 8 * i];
}

// -------------------------------------------------------------------------
// expert GEMM, 256x256 8-phase counted-vmcnt template (learn_hip m201-style)
//
//   512 threads = 8 waves (2M x 4N); per-wave output 128x64; BK=64.
//   LDS 128 KiB: [buf][A/B][half][128 rows][64 f16], double-buffered per
//   K-tile.  Swizzle: stage chunk = (tid&7)^(rowsel&7) on the GLOBAL source
//   (involution), un-applied on the ds_read side -> 2-way max bank aliasing.
//
//   Iteration = 2 K-tiles (kt0=2i -> buf0, kt1 -> buf1), 8 phases, each:
//     {ds_read subtile | issue 1 half-tile prefetch} ; s_barrier ;
//     lgkmcnt(0) ; setprio(1) ; 16 MFMA ; setprio(0) ; [vmcnt @p4/p8] ;
//     s_barrier
//   Stage map: p1:A1(kt1)  p2:A0(kt0+2) p3:B0(kt0+2) p4:B1(kt0+2)
//              p5:A1(kt0+2) p6:A0(kt0+3) p7:B0(kt0+3) p8:B1(kt0+3)
//   vmcnt ledger: steady p4/p8 see 14 outstanding, vmcnt(6) retires the
//   full next K-tile.  FINAL iteration: pf stages skipped -> drain with
//   vmcnt(0) (R4's replay-divergence root cause; verified fixed in R7).
//
//   NEW (R8):
//   - chunked XCD remap: L = x + y*NX; c=L&7; k=L>>3; slot=c*9+k%9;
//     ntile=k/9.  Each XCD owns 9 contiguous m-slots x all n-tiles ->
//     A-panels fetched once per XCD (A HBM/L3 traffic /8); e-sorted slots
//     keep B locality.  Bijective (nwg = NX*72, NX*72%8==0).
//   - fp16 epilogue: per-wave-private LDS transpose (16 x 68 fp16, 136B
//     stride: b64 reads land 2-way max on banks) -> row-major f16x8 16B
//     stores, full 128B segments.  Kills the 2.3x WRITE_SIZE (32B partial
//     lines -> TCC RMW) measured in R7.  fp32 path (L3) already emits full
//     64B segments -> unchanged.
// -------------------------------------------------------------------------
template <int K, int NOUT, bool GATHER, bool RELU, bool OUT_FP16>
__global__ __launch_bounds__(512) void gemm_expert(
    const fp16_t* __restrict__ A, const fp16_t* __restrict__ Wt,
    const float* __restrict__ bias, void* __restrict__ Cout,
    const int* __restrict__ offs, const int* __restrict__ pair_token,
    const int* __restrict__ tile_e, const int* __restrict__ tile_mt)
{
    const int NX = NOUT / 256;
    const int L = blockIdx.x + blockIdx.y * NX;
    const int xcd = L & 7, kk = L >> 3;
    const int slotI = xcd * 9 + kk % 9;          // 0..71
    const int ntile = kk / 9;                    // 0..NX-1

    const int e = tile_e[slotI];
    if (e < 0) return;
    const int mt  = tile_mt[slotI];
    const int off = offs[e];
    const int cnt = offs[e + 1] - off;
    const int rows_here = min(256, cnt - mt * 256);
    const int mb = off + mt * 256;
    const int n0 = ntile * 256;

    extern __shared__ __align__(16) char smem[];   // 131072 B

    const int tid = threadIdx.x, lane = tid & 63, wv = tid >> 6;
    const int wm = wv >> 2, wn = wv & 3;           // 2M x 4N wave grid
    const int l15 = lane & 15, quad = lane >> 4, sb = l15 & 7;

    // ---- staging lane constants --------------------------------------
    const int rowsel = tid >> 3;                         // 0..63
    const int coff = ((tid & 7) ^ (rowsel & 7)) * 8;     // swizzled chunk (elems)

    const fp16_t* We = Wt + (size_t)e * NOUT * K;

    // A stage pointers [half][substep]: tile row = rowsel + s*128 + h*64
    const fp16_t* aptr[2][2];
    #pragma unroll
    for (int h = 0; h < 2; ++h)
        #pragma unroll
        for (int s = 0; s < 2; ++s) {
            int tr = rowsel + s * 128 + h * 64;
            int rc = (tr < rows_here) ? tr : (rows_here - 1);
            long rowidx = GATHER ? (long)pair_token[mb + rc] : (long)(mb + rc);
            aptr[h][s] = A + rowidx * (long)K + coff;
        }
    // B stage base: n-row = n0 + nbase + s*128 + h*32
    const int nbase = (rowsel & 31) + (tid >> 8) * 64;
    const fp16_t* bptr = We + (size_t)(n0 + nbase) * K + coff;

    char* const ldsw = smem + wv * 1024;               // per-wave stage base

#define STAGE_A(h, kt) do {                                                  \
        int _b = ((kt) & 1) * 32768 + (h) * 16384;                           \
        load_lds16(aptr[h][0] + (kt) * 64, ldsw + _b);                       \
        load_lds16(aptr[h][1] + (kt) * 64, ldsw + _b + 8192); } while (0)

#define STAGE_B(h, kt) do {                                                  \
        int _b = 65536 + ((kt) & 1) * 32768 + (h) * 16384;                   \
        load_lds16(bptr + (size_t)((h) * 32) * K + (kt) * 64, ldsw + _b);    \
        load_lds16(bptr + (size_t)((h) * 32 + 128) * K + (kt) * 64,          \
                   ldsw + _b + 8192); } while (0)

    // ---- fragment-read lane constants --------------------------------
    const int slot0 = (quad ^ sb) * 16;            // ks=0 k-chunk slot
    const int slot1 = ((quad + 4) ^ sb) * 16;      // ks=1
    const int arow = (wm * 64 + l15) * 128;        // row-in-half * 128B
    const int brow = (wn * 32 + l15) * 128;

    f16x8 a[4][2], b0[2][2], b1[2][2];
    f32x4 acc[8][4] = {};

#define READ_A(buf, h) do {                                                  \
        _Pragma("unroll")                                                    \
        for (int ii = 0; ii < 4; ++ii) {                                     \
            int _b = (buf) * 32768 + (h) * 16384 + arow + ii * 2048;         \
            a[ii][0] = *(const f16x8*)(smem + _b + slot0);                   \
            a[ii][1] = *(const f16x8*)(smem + _b + slot1);                   \
        } } while (0)

#define READ_B(buf, h, br) do {                                              \
        _Pragma("unroll")                                                    \
        for (int jj = 0; jj < 2; ++jj) {                                     \
            int _b = 65536 + (buf) * 32768 + (h) * 16384 + brow + jj * 2048; \
            br[jj][0] = *(const f16x8*)(smem + _b + slot0);                  \
            br[jj][1] = *(const f16x8*)(smem + _b + slot1);                  \
        } } while (0)

#define MFMA_Q(imb, jnb, br) do {                                            \
        _Pragma("unroll")                                                    \
        for (int ks = 0; ks < 2; ++ks)                                       \
        _Pragma("unroll")                                                    \
        for (int ii = 0; ii < 4; ++ii)                                       \
        _Pragma("unroll")                                                    \
        for (int jj = 0; jj < 2; ++jj)                                       \
            acc[(imb) + ii][(jnb) + jj] =                                    \
                __builtin_amdgcn_mfma_f32_16x16x32_f16(                      \
                    a[ii][ks], br[jj][ks], acc[(imb) + ii][(jnb) + jj],      \
                    0, 0, 0); } while (0)

#define BAR() do { asm volatile("" ::: "memory");                            \
                   __builtin_amdgcn_s_barrier();                             \
                   asm volatile("" ::: "memory"); } while (0)
#define LGKM0() asm volatile("s_waitcnt lgkmcnt(0)" ::: "memory")
#define VM6()   asm volatile("s_waitcnt vmcnt(6)" ::: "memory")
#define VM0()   asm volatile("s_waitcnt vmcnt(0)" ::: "memory")

    // ---- prologue: K-tile 0 fully + A0,B0,B1 of K-tile 1 --------------
    STAGE_A(0, 0); STAGE_B(0, 0); STAGE_B(1, 0); STAGE_A(1, 0);   // 8 loads
    STAGE_A(0, 1); STAGE_B(0, 1); STAGE_B(1, 1);                  // 6 loads
    VM6();          // 14 -> 6: all of K-tile 0 landed; kt1's 6 in flight
    BAR();

    const int niter = K / 128;
    for (int i = 0; i < niter; ++i) {
        const int kt0 = 2 * i, kt1 = kt0 + 1;
        const bool pf = (i + 1 < niter);
        // p1: quadrant (m0..3, n0..1) of kt0
        READ_A(0, 0); READ_B(0, 0, b0);
        STAGE_A(1, kt1);
        BAR(); LGKM0();
        __builtin_amdgcn_s_setprio(1); MFMA_Q(0, 0, b0); __builtin_amdgcn_s_setprio(0);
        BAR();
        // p2: (m0..3, n2..3)
        READ_B(0, 1, b1);
        if (pf) STAGE_A(0, kt0 + 2);
        BAR(); LGKM0();
        __builtin_amdgcn_s_setprio(1); MFMA_Q(0, 2, b1); __builtin_amdgcn_s_setprio(0);
        BAR();
        // p3: (m4..7, n2..3)
        READ_A(0, 1);
        if (pf) STAGE_B(0, kt0 + 2);
        BAR(); LGKM0();
        __builtin_amdgcn_s_setprio(1); MFMA_Q(4, 2, b1); __builtin_amdgcn_s_setprio(0);
        BAR();
        // p4: (m4..7, n0..1)  -- no new ds_reads
        if (pf) STAGE_B(1, kt0 + 2);
        BAR();
        __builtin_amdgcn_s_setprio(1); MFMA_Q(4, 0, b0); __builtin_amdgcn_s_setprio(0);
        if (pf) VM6(); else VM0();   // ALL of kt1 landed before p5 reads it
        BAR();
        // p5: (m0..3, n0..1) of kt1
        READ_A(1, 0); READ_B(1, 0, b0);
        if (pf) STAGE_A(1, kt0 + 2);
        BAR(); LGKM0();
        __builtin_amdgcn_s_setprio(1); MFMA_Q(0, 0, b0); __builtin_amdgcn_s_setprio(0);
        BAR();
        // p6: (m0..3, n2..3)
        READ_B(1, 1, b1);
        if (pf) STAGE_A(0, kt0 + 3);
        BAR(); LGKM0();
        __builtin_amdgcn_s_setprio(1); MFMA_Q(0, 2, b1); __builtin_amdgcn_s_setprio(0);
        BAR();
        // p7: (m4..7, n2..3)
        READ_A(1, 1);
        if (pf) STAGE_B(0, kt0 + 3);
        BAR(); LGKM0();
        __builtin_amdgcn_s_setprio(1); MFMA_Q(4, 2, b1); __builtin_amdgcn_s_setprio(0);
        BAR();
        // p8: (m4..7, n0..1)
        if (pf) STAGE_B(1, kt0 + 3);
        BAR();
        __builtin_amdgcn_s_setprio(1); MFMA_Q(4, 0, b0); __builtin_amdgcn_s_setprio(0);
        if (pf) VM6(); else VM0();   // ALL of kt0+2 landed before next p1
        BAR();
    }

#undef STAGE_A
#undef STAGE_B
#undef READ_A
#undef READ_B
#undef MFMA_Q
#undef BAR
#undef LGKM0
#undef VM6
#undef VM0

    // ---- epilogue ------------------------------------------------------
    // acc layout: col = wn*64 + j*16 + l15, row = wm*128 + i2*16 + quad*4+r
    const float* be = bias + (size_t)e * NOUT + n0;
    float bv[4];
    #pragma unroll
    for (int j = 0; j < 4; ++j) bv[j] = be[wn * 64 + j * 16 + l15];

    if (OUT_FP16) {
        // per-wave-private LDS transpose: 16 rows x 68 fp16 (136B stride).
        // All waves passed the final BAR (vmcnt(0)-drained) -> LDS free.
        // DS ops from one wave execute in order -> no barriers needed.
        fp16_t* tb = (fp16_t*)(smem + wv * 4096);
        const int r8 = lane >> 3, c8 = lane & 7;     // read: row r8(+8), 8 cols
        #pragma unroll
        for (int i2 = 0; i2 < 8; ++i2) {
            #pragma unroll
            for (int j = 0; j < 4; ++j)
                #pragma unroll
                for (int r = 0; r < 4; ++r) {
                    float v = acc[i2][j][r] + bv[j];
                    if (RELU) v = fmaxf(v, 0.f);
                    tb[(quad * 4 + r) * 68 + j * 16 + l15] = (fp16_t)v;
                }
            #pragma unroll
            for (int pass = 0; pass < 2; ++pass) {
                int row = r8 + pass * 8;
                f16x4 lo = *(const f16x4*)&tb[row * 68 + c8 * 8];
                f16x4 hi = *(const f16x4*)&tb[row * 68 + c8 * 8 + 4];
                int m = wm * 128 + i2 * 16 + row;
                if (m < rows_here) {
                    f16x8 vv = { lo[0], lo[1], lo[2], lo[3],
                                 hi[0], hi[1], hi[2], hi[3] };
                    *(f16x8*)((fp16_t*)Cout + (size_t)(mb + m) * NOUT
                              + n0 + wn * 64 + c8 * 8) = vv;
                }
            }
        }
    } else {
        // fp32: 16 lanes x 4B = full 64B segments per quad-row already.
        #pragma unroll
        for (int j = 0; j < 4; ++j) {
            int col = wn * 64 + j * 16 + l15;
            #pragma unroll
            for (int i2 = 0; i2 < 8; ++i2) {
                int mrow0 = wm * 128 + i2 * 16 + quad * 4;
                #pragma unroll
                for (int r = 0; r < 4; ++r) {
                    int m = mrow0 + r;
                    if (m < rows_here) {
                        float v = acc[i2][j][r] + bv[j];
                        if (RELU) v = fmaxf(v, 0.f);
                        ((float*)Cout)[(size_t)(mb + m) * NOUT + n0 + col] = v;
                    }
                }
            }
        }
    }
}

// -------------------------------------------------------------------------
__global__ __launch_bounds__(256) void combine_kernel(
    const float* __restrict__ y, const int* __restrict__ slot,
    const float* __restrict__ top_w, float* __restrict__ out)
{
    int idx = blockIdx.x * 256 + threadIdx.x;    // over N_TOK * OUTD/4
    int n  = idx >> 8;                           // OUTD/4 = 256
    int o4 = idx & 255;
    int s0 = slot[n], s1 = slot[N_TOK + n];
    float w0 = top_w[n], w1 = top_w[N_TOK + n];
    float4 y0 = *(const float4*)(y + (size_t)s0 * OUTD + o4 * 4);
    float4 y1 = *(const float4*)(y + (size_t)s1 * OUTD + o4 * 4);
    float4 r;
    r.x = w0 * y0.x + w1 * y1.x;
    r.y = w0 * y0.y + w1 * y1.y;
    r.z = w0 * y0.z + w1 * y1.z;
    r.w = w0 * y0.w + w1 * y1.w;
    *(float4*)(out + (size_t)n * OUTD + o4 * 4) = r;
}

// -------------------------------------------------------------------------
extern "C" void kernel_launch(void* const* d_in, const int* in_sizes, int n_in,
                              void* d_out, int out_size, void* d_ws, size_t ws_size,
                              hipStream_t stream)
{
    (void)in_sizes; (void)n_in; (void)out_size; (void)ws_size;
    const float* x   = (const float*)d_in[0];
    const float* W1  = (const float*)d_in[1];
    const float* b1  = (const float*)d_in[2];
    const float* W2  = (const float*)d_in[3];
    const float* b2  = (const float*)d_in[4];
    const float* W3  = (const float*)d_in[5];
    const float* b3  = (const float*)d_in[6];
    const float* Wg1 = (const float*)d_in[7];
    const float* bg1 = (const float*)d_in[8];
    const float* Wg2 = (const float*)d_in[9];
    const float* bg2 = (const float*)d_in[10];

    // ws layout (bytes):
    //   xb   @ 0          : 16,777,216   (8192x1024 fp16)
    //   h1/y @ 16777216   : 67,108,864   (16384x2048 fp16 == 16384x1024 fp32)
    //   h2   @ 83886080   : 67,108,864
    //   Wt   @ 150994944  : 67,108,864   (max transposed W, fp16)
    //   rt   @ 218103808  : routing (~0.3 MB)
    char* ws = (char*)d_ws;
    fp16_t* xb = (fp16_t*)ws;
    fp16_t* h1 = (fp16_t*)(ws + 16777216);
    fp16_t* h2 = (fp16_t*)(ws + 83886080);
    fp16_t* Wt = (fp16_t*)(ws + 150994944);
    char* rt   = ws + 218103808;
    int*   offs       = (int*)rt;                    // 9
    int*   tile_e     = offs + 9;                    // MAXSLOT
    int*   tile_mt    = tile_e + MAXSLOT;            // MAXSLOT
    int*   top_i      = tile_mt + MAXSLOT;           // 2*N
    float* top_w      = (float*)(top_i + 2 * N_TOK); // 2*N
    int*   slot       = (int*)(top_w + 2 * N_TOK);   // 2*N
    int*   pair_token = slot + 2 * N_TOK;            // NPAIR
    int*   blockhist  = pair_token + NPAIR;          // HBLK*NE
    int*   pairbase   = blockhist + HBLK * NE;       // HBLK*NE

    gating_kernel<<<1024, 256, 0, stream>>>(x, Wg1, bg1, Wg2, bg2, top_i, top_w);
    hist_kernel<<<HBLK, 256, 0, stream>>>(top_i, blockhist);
    scan_kernel<<<1, HBLK * NE, 0, stream>>>(blockhist, offs, pairbase, tile_e, tile_mt);
    scatter_kernel<<<HBLK, 256, 0, stream>>>(top_i, pairbase, pair_token, slot);
    xcvt_kernel<<<8192, 256, 0, stream>>>(x, xb);

    // L1: h1 = relu(x @ W1[e] + b1[e])   (gathered rows, K=1024, NOUT=2048)
    transpose_cvt<<<dim3(HID / 32, DIM / 32, NE), 256, 0, stream>>>(W1, Wt, DIM, HID);
    gemm_expert<DIM, HID, true, true, true>
        <<<dim3(HID / 256, MAXSLOT), 512, 131072, stream>>>(
            xb, Wt, b1, (void*)h1, offs, pair_token, tile_e, tile_mt);

    // L2: h2 = relu(h1 @ W2[e] + b2[e])  (K=2048, NOUT=2048)
    transpose_cvt<<<dim3(HID / 32, HID / 32, NE), 256, 0, stream>>>(W2, Wt, HID, HID);
    gemm_expert<HID, HID, false, true, true>
        <<<dim3(HID / 256, MAXSLOT), 512, 131072, stream>>>(
            h1, Wt, b2, (void*)h2, offs, pair_token, tile_e, tile_mt);

    // L3: y = h2 @ W3[e] + b3[e]  (fp32 out into h1's buffer; K=2048, NOUT=1024)
    transpose_cvt<<<dim3(OUTD / 32, HID / 32, NE), 256, 0, stream>>>(W3, Wt, HID, OUTD);
    gemm_expert<HID, OUTD, false, false, false>
        <<<dim3(OUTD / 256, MAXSLOT), 512, 131072, stream>>>(
            h2, Wt, b3, (void*)h1, offs, pair_token, tile_e, tile_mt);

    combine_kernel<<<8192, 256, 0, stream>>>((const float*)h1, slot, top_w, (float*)d_out);
}

// Round 9
// 744.566 us; speedup vs baseline: 1.1768x; 1.0375x over previous
//
#include <hip/hip_runtime.h>

typedef _Float16 fp16_t;
typedef __attribute__((ext_vector_type(8))) _Float16 f16x8;
typedef __attribute__((ext_vector_type(4))) _Float16 f16x4;
typedef __attribute__((ext_vector_type(2))) _Float16 f16x2;
typedef __attribute__((ext_vector_type(4))) float f32x4;

#define N_TOK 8192
#define DIM   1024
#define HID   2048
#define OUTD  1024
#define NE    8
#define NPAIR 16384    // N_TOK * top_k
#define MAXSLOT 72     // m-tiles of 256: 16384/256 + 8 partials
#define HBLK 64        // hist/scatter blocks (256 pairs each)

// -------------------------------------------------------------------------
// async global->LDS, 16B per lane (wave-uniform LDS base + lane*16; global
// address may be per-lane)
// -------------------------------------------------------------------------
__device__ __forceinline__ void load_lds16(const void* g, void* l) {
    __builtin_amdgcn_global_load_lds(
        (__attribute__((address_space(1))) void*)g,
        (__attribute__((address_space(3))) void*)l, 16, 0, 0);
}

// -------------------------------------------------------------------------
// gating: fp32, one wave handles 2 tokens (x rows staged in LDS).
// NO atomics (routing counts derived by hist/scan/scatter below).
// top-2 ties -> lower index (matches jax.lax.top_k); combine weight = the
// ORIGINAL gate value.
// -------------------------------------------------------------------------
__global__ __launch_bounds__(256) void gating_kernel(
    const float* __restrict__ x,  const float* __restrict__ Wg1,
    const float* __restrict__ bg1, const float* __restrict__ Wg2,
    const float* __restrict__ bg2,
    int* __restrict__ top_i, float* __restrict__ top_w)
{
    __shared__ float xs[8][DIM];            // 32 KB: 8 token rows
    const int tid = threadIdx.x, lane = tid & 63, wv = tid >> 6;

    const float4* x4 = (const float4*)(x + (size_t)blockIdx.x * 8 * DIM);
    float4* xs4 = (float4*)&xs[0][0];
    #pragma unroll
    for (int i = 0; i < 8; ++i) xs4[tid + 256 * i] = x4[tid + 256 * i];
    __syncthreads();

    const int trow = wv * 2;                // wave owns tokens trow, trow+1
    const float b = bg1[lane];              // lane owns hidden unit 'lane'
    float h00 = b,   h01 = 0.f;             // token 0: even/odd-quad chains
    float h10 = b,   h11 = 0.f;             // token 1
    for (int d0 = 0; d0 < DIM; d0 += 8) {
        float w[8];
        #pragma unroll
        for (int i = 0; i < 8; ++i) w[i] = Wg1[(d0 + i) * 64 + lane];
        float4 a00 = *(const float4*)&xs[trow][d0];
        float4 a01 = *(const float4*)&xs[trow][d0 + 4];
        float4 a10 = *(const float4*)&xs[trow + 1][d0];
        float4 a11 = *(const float4*)&xs[trow + 1][d0 + 4];
        h00 = fmaf(a00.x, w[0], fmaf(a00.y, w[1], fmaf(a00.z, w[2], fmaf(a00.w, w[3], h00))));
        h01 = fmaf(a01.x, w[4], fmaf(a01.y, w[5], fmaf(a01.z, w[6], fmaf(a01.w, w[7], h01))));
        h10 = fmaf(a10.x, w[0], fmaf(a10.y, w[1], fmaf(a10.z, w[2], fmaf(a10.w, w[3], h10))));
        h11 = fmaf(a11.x, w[4], fmaf(a11.y, w[5], fmaf(a11.z, w[6], fmaf(a11.w, w[7], h11))));
    }
    float hg[2] = { h00 + h01, h10 + h11 };

    #pragma unroll
    for (int t = 0; t < 2; ++t) {
        float h = fmaxf(hg[t], 0.f);
        float p[NE];
        #pragma unroll
        for (int e = 0; e < NE; ++e) p[e] = h * Wg2[lane * NE + e];
        #pragma unroll
        for (int s = 32; s > 0; s >>= 1) {
            #pragma unroll
            for (int e = 0; e < NE; ++e) p[e] += __shfl_xor(p[e], s, 64);
        }
        if (lane == 0) {
            int n = blockIdx.x * 8 + trow + t;
            float g[NE];
            float m = -1e30f;
            #pragma unroll
            for (int e = 0; e < NE; ++e) { g[e] = p[e] + bg2[e]; m = fmaxf(m, g[e]); }
            float s = 0.f;
            #pragma unroll
            for (int e = 0; e < NE; ++e) { g[e] = expf(g[e] - m); s += g[e]; }
            float inv = 1.f / s;
            #pragma unroll
            for (int e = 0; e < NE; ++e) g[e] *= inv;
            int b0 = 0;
            #pragma unroll
            for (int e = 1; e < NE; ++e) if (g[e] > g[b0]) b0 = e;
            int b1 = (b0 == 0) ? 1 : 0;
            #pragma unroll
            for (int e = 0; e < NE; ++e) if (e != b0 && g[e] > g[b1]) b1 = e;
            top_i[n] = b0;          top_i[N_TOK + n] = b1;
            top_w[n] = g[b0];       top_w[N_TOK + n] = g[b1];
        }
    }
}

// -------------------------------------------------------------------------
// hist: per-block expert histogram of the 2N pair stream via wave ballots.
// 64 blocks x 256 threads, 1 pair/thread. Zero atomics.
// -------------------------------------------------------------------------
__global__ __launch_bounds__(256) void hist_kernel(
    const int* __restrict__ top_i, int* __restrict__ blockhist)
{
    __shared__ int wh[4][NE];
    const int tid = threadIdx.x, lane = tid & 63, wv = tid >> 6;
    const int e = top_i[blockIdx.x * 256 + tid];
    #pragma unroll
    for (int e0 = 0; e0 < NE; ++e0) {
        unsigned long long m = __ballot(e == e0);
        if (lane == 0) wh[wv][e0] = __popcll(m);
    }
    __syncthreads();
    if (tid < NE)
        blockhist[blockIdx.x * NE + tid] =
            wh[0][tid] + wh[1][tid] + wh[2][tid] + wh[3][tid];
}

// -------------------------------------------------------------------------
// scan: counts/offs/per-block bases + m-tile table (slot -> expert, m-tile).
// Single block; all in LDS.
// -------------------------------------------------------------------------
__global__ __launch_bounds__(512) void scan_kernel(
    const int* __restrict__ blockhist, int* __restrict__ offs,
    int* __restrict__ pairbase,
    int* __restrict__ tile_e, int* __restrict__ tile_mt)
{
    __shared__ int h[HBLK * NE], pb[HBLK * NE], off_s[NE + 1];
    const int tid = threadIdx.x;
    h[tid] = blockhist[tid];
    __syncthreads();
    if (tid == 0) {
        int c[NE] = {};
        for (int b = 0; b < HBLK; ++b)
            #pragma unroll
            for (int e = 0; e < NE; ++e) { pb[b * NE + e] = c[e]; c[e] += h[b * NE + e]; }
        int acc = 0;
        #pragma unroll
        for (int e = 0; e < NE; ++e) { off_s[e] = acc; acc += c[e]; }
        off_s[NE] = acc;
        for (int e = 0; e <= NE; ++e) offs[e] = off_s[e];
        int s = 0;
        for (int e = 0; e < NE; ++e) {
            int nt = (c[e] + 255) >> 8;
            for (int mt = 0; mt < nt; ++mt) { tile_e[s] = e; tile_mt[s] = mt; ++s; }
        }
        for (; s < MAXSLOT; ++s) tile_e[s] = -1;
    }
    __syncthreads();
    pairbase[tid] = pb[tid] + off_s[tid & (NE - 1)];
}

// -------------------------------------------------------------------------
// scatter: deterministic slot assignment. rank = pairbase[blk][e]
//   + (rank of my wave's earlier waves in this block for e)
//   + (my rank among lanes of my wave with expert e).  Zero atomics.
// -------------------------------------------------------------------------
__global__ __launch_bounds__(256) void scatter_kernel(
    const int* __restrict__ top_i, const int* __restrict__ pairbase,
    int* __restrict__ pair_token, int* __restrict__ slot)
{
    __shared__ int wh[4][NE];
    const int tid = threadIdx.x, lane = tid & 63, wv = tid >> 6;
    const int p = blockIdx.x * 256 + tid;
    const int e = top_i[p];
    int myrank = 0;
    #pragma unroll
    for (int e0 = 0; e0 < NE; ++e0) {
        unsigned long long m = __ballot(e == e0);
        if (lane == 0) wh[wv][e0] = __popcll(m);
        if (e == e0) myrank = __popcll(m & ((1ull << lane) - 1ull));
    }
    __syncthreads();
    int wprefix = 0;
    for (int w = 0; w < wv; ++w) wprefix += wh[w][e];
    const int pout = pairbase[blockIdx.x * NE + e] + wprefix + myrank;
    pair_token[pout] = p & (N_TOK - 1);      // p = s*N + n, N power of two
    slot[p] = pout;
}

// -------------------------------------------------------------------------
__global__ __launch_bounds__(256) void xcvt_kernel(
    const float* __restrict__ x, fp16_t* __restrict__ xb)
{
    size_t i = ((size_t)blockIdx.x * 256 + threadIdx.x) * 4;
    float4 v = *(const float4*)(x + i);
    f16x4 o = { (fp16_t)v.x, (fp16_t)v.y, (fp16_t)v.z, (fp16_t)v.w };
    *(f16x4*)(xb + i) = o;
}

// -------------------------------------------------------------------------
// batched transpose+convert: src fp32 [batch][R][C] -> dst fp16 [batch][C][R]
// 64(R) x 32(C) tile; f16x2 stores -> full 128B segments per wave-instr
// (scalar 2B stores gave 64B partials -> TCC RMW).  Requires R%64==0.
// -------------------------------------------------------------------------
__global__ __launch_bounds__(256) void transpose_cvt(
    const float* __restrict__ src, fp16_t* __restrict__ dst, int R, int C)
{
    int bb = blockIdx.z;
    src += (size_t)bb * R * C;
    dst += (size_t)bb * R * C;
    __shared__ float sm[64][33];
    int tx = threadIdx.x & 31, ty = threadIdx.x >> 5;   // 32 x 8
    int r0 = blockIdx.y * 64, c0 = blockIdx.x * 32;
    #pragma unroll
    for (int i = 0; i < 8; ++i)
        sm[ty + 8 * i][tx] = src[(size_t)(r0 + ty + 8 * i) * C + c0 + tx];
    __syncthreads();
    #pragma unroll
    for (int i = 0; i < 4; ++i) {
        int crow = ty + 8 * i;
        f16x2 v = { (fp16_t)sm[tx * 2][crow], (fp16_t)sm[tx * 2 + 1][crow] };
        *(f16x2*)&dst[(size_t)(c0 + crow) * R + r0 + tx * 2] = v;
    }
}

// -------------------------------------------------------------------------
// expert GEMM, 256x256 8-phase counted-vmcnt template (learn_hip m201-style)
//
//   512 threads = 8 waves (2M x 4N); per-wave output 128x64; BK=64.
//   LDS 128 KiB: [buf][A/B][half][128 rows][64 f16], double-buffered per
//   K-tile.  Swizzle: stage chunk = (tid&7)^(rowsel&7) on the GLOBAL source
//   (involution), un-applied on the ds_read side -> 2-way max bank aliasing.
//
//   Iteration = 2 K-tiles (kt0=2i -> buf0, kt1 -> buf1), 8 phases, each:
//     {ds_read subtile | issue 1 half-tile prefetch} ; s_barrier ;
//     lgkmcnt(0) ; setprio(1) ; 16 MFMA ; setprio(0) ; [vmcnt @p4/p8] ;
//     s_barrier
//   Stage map: p1:A1(kt1)  p2:A0(kt0+2) p3:B0(kt0+2) p4:B1(kt0+2)
//              p5:A1(kt0+2) p6:A0(kt0+3) p7:B0(kt0+3) p8:B1(kt0+3)
//   vmcnt ledger: steady p4/p8 see 14 outstanding, vmcnt(6) retires the
//   full next K-tile.  FINAL iteration: pf stages skipped -> drain with
//   vmcnt(0) (R4's replay-divergence root cause; verified fixed in R7).
//
//   KSPLIT (R9): block handles K-range [ks*K/KSPLIT, (ks+1)*K/KSPLIT);
//   identical instruction pattern / vmcnt ledger, just fewer iterations.
//   fp16 partial outputs go to Cout + ks*NPAIR*NOUT.  Fixes L3's 51.5%
//   grid packing (264 blocks/2 rounds -> 528 half-blocks/3 rounds).
//   ADD_BIAS=false defers bias to combine (which knows top_i).
//
//   chunked XCD remap: L = bx + by*NX; each XCD owns 9 contiguous m-slots
//   x all n-tiles -> A-panels fetched ~once per XCD.  fp16 epilogue via
//   per-wave LDS transpose -> full 128B store segments (R8, verified).
// -------------------------------------------------------------------------
template <int K, int NOUT, bool GATHER, bool RELU, bool OUT_FP16,
          int KSPLIT, bool ADD_BIAS>
__global__ __launch_bounds__(512) void gemm_expert(
    const fp16_t* __restrict__ A, const fp16_t* __restrict__ Wt,
    const float* __restrict__ bias, void* __restrict__ Cout,
    const int* __restrict__ offs, const int* __restrict__ pair_token,
    const int* __restrict__ tile_e, const int* __restrict__ tile_mt)
{
    const int NX = NOUT / 256;
    const int bx = blockIdx.x / KSPLIT;
    const int ks = blockIdx.x % KSPLIT;
    const int KLOC = K / KSPLIT;
    const int L = bx + blockIdx.y * NX;
    const int xcd = L & 7, kk = L >> 3;
    const int slotI = xcd * 9 + kk % 9;          // 0..71
    const int ntile = kk / 9;                    // 0..NX-1

    const int e = tile_e[slotI];
    if (e < 0) return;
    const int mt  = tile_mt[slotI];
    const int off = offs[e];
    const int cnt = offs[e + 1] - off;
    const int rows_here = min(256, cnt - mt * 256);
    const int mb = off + mt * 256;
    const int n0 = ntile * 256;

    extern __shared__ __align__(16) char smem[];   // 131072 B

    const int tid = threadIdx.x, lane = tid & 63, wv = tid >> 6;
    const int wm = wv >> 2, wn = wv & 3;           // 2M x 4N wave grid
    const int l15 = lane & 15, quad = lane >> 4, sb = l15 & 7;

    // ---- staging lane constants --------------------------------------
    const int rowsel = tid >> 3;                         // 0..63
    const int coff = ((tid & 7) ^ (rowsel & 7)) * 8;     // swizzled chunk (elems)

    const fp16_t* We = Wt + (size_t)e * NOUT * K;

    // A stage pointers [half][substep]: tile row = rowsel + s*128 + h*64
    const fp16_t* aptr[2][2];
    #pragma unroll
    for (int h = 0; h < 2; ++h)
        #pragma unroll
        for (int s = 0; s < 2; ++s) {
            int tr = rowsel + s * 128 + h * 64;
            int rc = (tr < rows_here) ? tr : (rows_here - 1);
            long rowidx = GATHER ? (long)pair_token[mb + rc] : (long)(mb + rc);
            aptr[h][s] = A + rowidx * (long)K + ks * KLOC + coff;
        }
    // B stage base: n-row = n0 + nbase + s*128 + h*32
    const int nbase = (rowsel & 31) + (tid >> 8) * 64;
    const fp16_t* bptr = We + (size_t)(n0 + nbase) * K + ks * KLOC + coff;

    char* const ldsw = smem + wv * 1024;               // per-wave stage base

#define STAGE_A(h, kt) do {                                                  \
        int _b = ((kt) & 1) * 32768 + (h) * 16384;                           \
        load_lds16(aptr[h][0] + (kt) * 64, ldsw + _b);                       \
        load_lds16(aptr[h][1] + (kt) * 64, ldsw + _b + 8192); } while (0)

#define STAGE_B(h, kt) do {                                                  \
        int _b = 65536 + ((kt) & 1) * 32768 + (h) * 16384;                   \
        load_lds16(bptr + (size_t)((h) * 32) * K + (kt) * 64, ldsw + _b);    \
        load_lds16(bptr + (size_t)((h) * 32 + 128) * K + (kt) * 64,          \
                   ldsw + _b + 8192); } while (0)

    // ---- fragment-read lane constants --------------------------------
    const int slot0 = (quad ^ sb) * 16;            // ks=0 k-chunk slot
    const int slot1 = ((quad + 4) ^ sb) * 16;      // ks=1
    const int arow = (wm * 64 + l15) * 128;        // row-in-half * 128B
    const int brow = (wn * 32 + l15) * 128;

    f16x8 a[4][2], b0[2][2], b1[2][2];
    f32x4 acc[8][4] = {};

#define READ_A(buf, h) do {                                                  \
        _Pragma("unroll")                                                    \
        for (int ii = 0; ii < 4; ++ii) {                                     \
            int _b = (buf) * 32768 + (h) * 16384 + arow + ii * 2048;         \
            a[ii][0] = *(const f16x8*)(smem + _b + slot0);                   \
            a[ii][1] = *(const f16x8*)(smem + _b + slot1);                   \
        } } while (0)

#define READ_B(buf, h, br) do {                                              \
        _Pragma("unroll")                                                    \
        for (int jj = 0; jj < 2; ++jj) {                                     \
            int _b = 65536 + (buf) * 32768 + (h) * 16384 + brow + jj * 2048; \
            br[jj][0] = *(const f16x8*)(smem + _b + slot0);                  \
            br[jj][1] = *(const f16x8*)(smem + _b + slot1);                  \
        } } while (0)

#define MFMA_Q(imb, jnb, br) do {                                            \
        _Pragma("unroll")                                                    \
        for (int kq = 0; kq < 2; ++kq)                                       \
        _Pragma("unroll")                                                    \
        for (int ii = 0; ii < 4; ++ii)                                       \
        _Pragma("unroll")                                                    \
        for (int jj = 0; jj < 2; ++jj)                                       \
            acc[(imb) + ii][(jnb) + jj] =                                    \
                __builtin_amdgcn_mfma_f32_16x16x32_f16(                      \
                    a[ii][kq], br[jj][kq], acc[(imb) + ii][(jnb) + jj],      \
                    0, 0, 0); } while (0)

#define BAR() do { asm volatile("" ::: "memory");                            \
                   __builtin_amdgcn_s_barrier();                             \
                   asm volatile("" ::: "memory"); } while (0)
#define LGKM0() asm volatile("s_waitcnt lgkmcnt(0)" ::: "memory")
#define VM6()   asm volatile("s_waitcnt vmcnt(6)" ::: "memory")
#define VM0()   asm volatile("s_waitcnt vmcnt(0)" ::: "memory")

    // ---- prologue: K-tile 0 fully + A0,B0,B1 of K-tile 1 --------------
    STAGE_A(0, 0); STAGE_B(0, 0); STAGE_B(1, 0); STAGE_A(1, 0);   // 8 loads
    STAGE_A(0, 1); STAGE_B(0, 1); STAGE_B(1, 1);                  // 6 loads
    VM6();          // 14 -> 6: all of K-tile 0 landed; kt1's 6 in flight
    BAR();

    const int niter = KLOC / 128;
    for (int i = 0; i < niter; ++i) {
        const int kt0 = 2 * i, kt1 = kt0 + 1;
        const bool pf = (i + 1 < niter);
        // p1: quadrant (m0..3, n0..1) of kt0
        READ_A(0, 0); READ_B(0, 0, b0);
        STAGE_A(1, kt1);
        BAR(); LGKM0();
        __builtin_amdgcn_s_setprio(1); MFMA_Q(0, 0, b0); __builtin_amdgcn_s_setprio(0);
        BAR();
        // p2: (m0..3, n2..3)
        READ_B(0, 1, b1);
        if (pf) STAGE_A(0, kt0 + 2);
        BAR(); LGKM0();
        __builtin_amdgcn_s_setprio(1); MFMA_Q(0, 2, b1); __builtin_amdgcn_s_setprio(0);
        BAR();
        // p3: (m4..7, n2..3)
        READ_A(0, 1);
        if (pf) STAGE_B(0, kt0 + 2);
        BAR(); LGKM0();
        __builtin_amdgcn_s_setprio(1); MFMA_Q(4, 2, b1); __builtin_amdgcn_s_setprio(0);
        BAR();
        // p4: (m4..7, n0..1)  -- no new ds_reads
        if (pf) STAGE_B(1, kt0 + 2);
        BAR();
        __builtin_amdgcn_s_setprio(1); MFMA_Q(4, 0, b0); __builtin_amdgcn_s_setprio(0);
        if (pf) VM6(); else VM0();   // ALL of kt1 landed before p5 reads it
        BAR();
        // p5: (m0..3, n0..1) of kt1
        READ_A(1, 0); READ_B(1, 0, b0);
        if (pf) STAGE_A(1, kt0 + 2);
        BAR(); LGKM0();
        __builtin_amdgcn_s_setprio(1); MFMA_Q(0, 0, b0); __builtin_amdgcn_s_setprio(0);
        BAR();
        // p6: (m0..3, n2..3)
        READ_B(1, 1, b1);
        if (pf) STAGE_A(0, kt0 + 3);
        BAR(); LGKM0();
        __builtin_amdgcn_s_setprio(1); MFMA_Q(0, 2, b1); __builtin_amdgcn_s_setprio(0);
        BAR();
        // p7: (m4..7, n2..3)
        READ_A(1, 1);
        if (pf) STAGE_B(0, kt0 + 3);
        BAR(); LGKM0();
        __builtin_amdgcn_s_setprio(1); MFMA_Q(4, 2, b1); __builtin_amdgcn_s_setprio(0);
        BAR();
        // p8: (m4..7, n0..1)
        if (pf) STAGE_B(1, kt0 + 3);
        BAR();
        __builtin_amdgcn_s_setprio(1); MFMA_Q(4, 0, b0); __builtin_amdgcn_s_setprio(0);
        if (pf) VM6(); else VM0();   // ALL of kt0+2 landed before next p1
        BAR();
    }

#undef STAGE_A
#undef STAGE_B
#undef READ_A
#undef READ_B
#undef MFMA_Q
#undef BAR
#undef LGKM0
#undef VM6
#undef VM0

    // ---- epilogue ------------------------------------------------------
    // acc layout: col = wn*64 + j*16 + l15, row = wm*128 + i2*16 + quad*4+r
    const float* be = bias + (size_t)e * NOUT + n0;
    float bv[4];
    #pragma unroll
    for (int j = 0; j < 4; ++j)
        bv[j] = ADD_BIAS ? be[wn * 64 + j * 16 + l15] : 0.f;

    if (OUT_FP16) {
        // per-wave-private LDS transpose: 16 rows x 68 fp16 (136B stride).
        // All waves passed the final BAR (vmcnt(0)-drained) -> LDS free.
        fp16_t* outp = (fp16_t*)Cout + (size_t)ks * ((size_t)NPAIR * NOUT);
        fp16_t* tb = (fp16_t*)(smem + wv * 4096);
        const int r8 = lane >> 3, c8 = lane & 7;     // read: row r8(+8), 8 cols
        #pragma unroll
        for (int i2 = 0; i2 < 8; ++i2) {
            #pragma unroll
            for (int j = 0; j < 4; ++j)
                #pragma unroll
                for (int r = 0; r < 4; ++r) {
                    float v = acc[i2][j][r] + bv[j];
                    if (RELU) v = fmaxf(v, 0.f);
                    tb[(quad * 4 + r) * 68 + j * 16 + l15] = (fp16_t)v;
                }
            #pragma unroll
            for (int pass = 0; pass < 2; ++pass) {
                int row = r8 + pass * 8;
                f16x4 lo = *(const f16x4*)&tb[row * 68 + c8 * 8];
                f16x4 hi = *(const f16x4*)&tb[row * 68 + c8 * 8 + 4];
                int m = wm * 128 + i2 * 16 + row;
                if (m < rows_here) {
                    f16x8 vv = { lo[0], lo[1], lo[2], lo[3],
                                 hi[0], hi[1], hi[2], hi[3] };
                    *(f16x8*)(outp + (size_t)(mb + m) * NOUT
                              + n0 + wn * 64 + c8 * 8) = vv;
                }
            }
        }
    } else {
        // fp32: 16 lanes x 4B = full 64B segments per quad-row already.
        #pragma unroll
        for (int j = 0; j < 4; ++j) {
            int col = wn * 64 + j * 16 + l15;
            #pragma unroll
            for (int i2 = 0; i2 < 8; ++i2) {
                int mrow0 = wm * 128 + i2 * 16 + quad * 4;
                #pragma unroll
                for (int r = 0; r < 4; ++r) {
                    int m = mrow0 + r;
                    if (m < rows_here) {
                        float v = acc[i2][j][r] + bv[j];
                        if (RELU) v = fmaxf(v, 0.f);
                        ((float*)Cout)[(size_t)(mb + m) * NOUT + n0 + col] = v;
                    }
                }
            }
        }
    }
}

// -------------------------------------------------------------------------
// combine: out[n] = w0*(yA[s0]+yB[s0]+b3[e0]) + w1*(yA[s1]+yB[s1]+b3[e1])
// y partials are fp16 (split-K L3); bias applied here (gemm ran ADD_BIAS=0).
// -------------------------------------------------------------------------
__global__ __launch_bounds__(256) void combine_kernel(
    const fp16_t* __restrict__ y, const int* __restrict__ slot,
    const int* __restrict__ top_i, const float* __restrict__ top_w,
    const float* __restrict__ b3, float* __restrict__ out)
{
    int idx = blockIdx.x * 256 + threadIdx.x;    // over N_TOK * OUTD/8
    int n  = idx >> 7;                           // OUTD/8 = 128
    int o8 = (idx & 127) * 8;
    int s0 = slot[n], s1 = slot[N_TOK + n];
    int e0 = top_i[n], e1 = top_i[N_TOK + n];
    float w0 = top_w[n], w1 = top_w[N_TOK + n];
    const fp16_t* yB = y + (size_t)NPAIR * OUTD;
    f16x8 a0 = *(const f16x8*)(y  + (size_t)s0 * OUTD + o8);
    f16x8 p0 = *(const f16x8*)(yB + (size_t)s0 * OUTD + o8);
    f16x8 a1 = *(const f16x8*)(y  + (size_t)s1 * OUTD + o8);
    f16x8 p1 = *(const f16x8*)(yB + (size_t)s1 * OUTD + o8);
    const float* bb0 = b3 + (size_t)e0 * OUTD + o8;
    const float* bb1 = b3 + (size_t)e1 * OUTD + o8;
    float r[8];
    #pragma unroll
    for (int j = 0; j < 8; ++j)
        r[j] = w0 * ((float)a0[j] + (float)p0[j] + bb0[j])
             + w1 * ((float)a1[j] + (float)p1[j] + bb1[j]);
    float4 lo = { r[0], r[1], r[2], r[3] };
    float4 hi = { r[4], r[5], r[6], r[7] };
    *(float4*)(out + (size_t)n * OUTD + o8)     = lo;
    *(float4*)(out + (size_t)n * OUTD + o8 + 4) = hi;
}

// -------------------------------------------------------------------------
extern "C" void kernel_launch(void* const* d_in, const int* in_sizes, int n_in,
                              void* d_out, int out_size, void* d_ws, size_t ws_size,
                              hipStream_t stream)
{
    (void)in_sizes; (void)n_in; (void)out_size; (void)ws_size;
    const float* x   = (const float*)d_in[0];
    const float* W1  = (const float*)d_in[1];
    const float* b1  = (const float*)d_in[2];
    const float* W2  = (const float*)d_in[3];
    const float* b2  = (const float*)d_in[4];
    const float* W3  = (const float*)d_in[5];
    const float* b3  = (const float*)d_in[6];
    const float* Wg1 = (const float*)d_in[7];
    const float* bg1 = (const float*)d_in[8];
    const float* Wg2 = (const float*)d_in[9];
    const float* bg2 = (const float*)d_in[10];

    // ws layout (bytes):
    //   xb   @ 0          : 16,777,216   (8192x1024 fp16)
    //   h1/y @ 16777216   : 67,108,864   (16384x2048 fp16; L3: 2x fp16 y-partials)
    //   h2   @ 83886080   : 67,108,864
    //   Wt   @ 150994944  : 67,108,864   (max transposed W, fp16)
    //   rt   @ 218103808  : routing (~0.3 MB)
    char* ws = (char*)d_ws;
    fp16_t* xb = (fp16_t*)ws;
    fp16_t* h1 = (fp16_t*)(ws + 16777216);
    fp16_t* h2 = (fp16_t*)(ws + 83886080);
    fp16_t* Wt = (fp16_t*)(ws + 150994944);
    char* rt   = ws + 218103808;
    int*   offs       = (int*)rt;                    // 9
    int*   tile_e     = offs + 9;                    // MAXSLOT
    int*   tile_mt    = tile_e + MAXSLOT;            // MAXSLOT
    int*   top_i      = tile_mt + MAXSLOT;           // 2*N
    float* top_w      = (float*)(top_i + 2 * N_TOK); // 2*N
    int*   slot       = (int*)(top_w + 2 * N_TOK);   // 2*N
    int*   pair_token = slot + 2 * N_TOK;            // NPAIR
    int*   blockhist  = pair_token + NPAIR;          // HBLK*NE
    int*   pairbase   = blockhist + HBLK * NE;       // HBLK*NE

    gating_kernel<<<1024, 256, 0, stream>>>(x, Wg1, bg1, Wg2, bg2, top_i, top_w);
    hist_kernel<<<HBLK, 256, 0, stream>>>(top_i, blockhist);
    scan_kernel<<<1, HBLK * NE, 0, stream>>>(blockhist, offs, pairbase, tile_e, tile_mt);
    scatter_kernel<<<HBLK, 256, 0, stream>>>(top_i, pairbase, pair_token, slot);
    xcvt_kernel<<<8192, 256, 0, stream>>>(x, xb);

    // L1: h1 = relu(x @ W1[e] + b1[e])   (gathered rows, K=1024, NOUT=2048)
    transpose_cvt<<<dim3(HID / 32, DIM / 64, NE), 256, 0, stream>>>(W1, Wt, DIM, HID);
    gemm_expert<DIM, HID, true, true, true, 1, true>
        <<<dim3(HID / 256, MAXSLOT), 512, 131072, stream>>>(
            xb, Wt, b1, (void*)h1, offs, pair_token, tile_e, tile_mt);

    // L2: h2 = relu(h1 @ W2[e] + b2[e])  (K=2048, NOUT=2048)
    transpose_cvt<<<dim3(HID / 32, HID / 64, NE), 256, 0, stream>>>(W2, Wt, HID, HID);
    gemm_expert<HID, HID, false, true, true, 1, true>
        <<<dim3(HID / 256, MAXSLOT), 512, 131072, stream>>>(
            h1, Wt, b2, (void*)h2, offs, pair_token, tile_e, tile_mt);

    // L3: y = h2 @ W3[e]  (split-K=2, fp16 partials into h1 region;
    //     bias b3 deferred to combine)
    transpose_cvt<<<dim3(OUTD / 32, HID / 64, NE), 256, 0, stream>>>(W3, Wt, HID, OUTD);
    gemm_expert<HID, OUTD, false, false, true, 2, false>
        <<<dim3((OUTD / 256) * 2, MAXSLOT), 512, 131072, stream>>>(
            h2, Wt, b3, (void*)h1, offs, pair_token, tile_e, tile_mt);

    combine_kernel<<<N_TOK * (OUTD / 8) / 256, 256, 0, stream>>>(
        h1, slot, top_i, top_w, b3, (float*)d_out);
}